// Round 9
// baseline (598.366 us; speedup 1.0000x reference)
//
#include <hip/hip_runtime.h>
#include <hip/hip_bf16.h>
#include <math.h>

// ---------------------------------------------------------------------------
// Seq_HyGAN round 9:
//  * Wfl folded into all downstream weights -> M-row feat_e GEMM eliminated;
//    single batched gemm_m (efeat -> kt|v bf16 kv-table + qt_e f32) with
//    32x64 tiles / 32KB LDS / 1878 blocks (grid-fill + occupancy fix).
//  * attn_s1 processes nodes in degree-sorted order (nperm) -> removes the
//    max-of-4-Poisson wave divergence inflation (~1.5x).
//  * CSR counting-sort build, 16-lane-group attention, algebra folds kept.
// ---------------------------------------------------------------------------

#define HY_M 10000
#define HY_N 100000
#define HY_E 640000

#define SH_N 9              // node bucket width 512
#define NB_N 196            // ceil(100000/512)
#define SH_M 6              // hedge bucket width 64
#define NB_M 157            // ceil(10000/64)

// ---- bf16 helpers (manual, RN) ----
__device__ __forceinline__ unsigned int f2bf(float x) {
    unsigned int u = __float_as_uint(x);
    return (u + 0x7fffu + ((u >> 16) & 1u)) >> 16;
}
__device__ __forceinline__ float2 bf2x2(unsigned int w) {
    float lo = __uint_as_float(w << 16);
    float hi = __uint_as_float(w & 0xffff0000u);
    return make_float2(lo, hi);
}

// ---------------- small utility kernels ----------------
__global__ void zero_ints(int* __restrict__ p, int n) {
    int i = blockIdx.x * blockDim.x + threadIdx.x;
    if (i < n) p[i] = 0;
}

__global__ void fillk(float* __restrict__ p, float v, int n) {
    int stride = gridDim.x * blockDim.x;
    for (int i = blockIdx.x * blockDim.x + threadIdx.x; i < n; i += stride) p[i] = v;
}

// ---------------- CSR build: bucketed counting sort ----------------
__launch_bounds__(256)
__global__ void coarse_hist(const int* __restrict__ nd, const int* __restrict__ he,
                            int* __restrict__ gcntN, int* __restrict__ gcntM, int E) {
    __shared__ int hN[256], hM[256];
    const int t = threadIdx.x;
    hN[t] = 0; hM[t] = 0;
    __syncthreads();
    const int base = blockIdx.x * 4096;
    for (int i = t; i < 4096; i += 256) {
        int e = base + i;
        if (e < E) {
            atomicAdd(&hN[nd[e] >> SH_N], 1);
            atomicAdd(&hM[he[e] >> SH_M], 1);
        }
    }
    __syncthreads();
    if (hN[t]) atomicAdd(&gcntN[t], hN[t]);
    if (hM[t]) atomicAdd(&gcntM[t], hM[t]);
}

__global__ void coarse_scan(const int* __restrict__ gcntN, const int* __restrict__ gcntM,
                            int* __restrict__ coffN, int* __restrict__ coffM, int E) {
    __shared__ int s[256];
    const int* g = blockIdx.x ? gcntM : gcntN;
    int* o = blockIdx.x ? coffM : coffN;
    const int nb = blockIdx.x ? NB_M : NB_N;
    const int t = threadIdx.x;
    int v = (t < nb) ? g[t] : 0;
    int orig = v;
    s[t] = v; __syncthreads();
    for (int off = 1; off < 256; off <<= 1) {
        int x = (t >= off) ? s[t - off] : 0;
        __syncthreads(); s[t] += x; __syncthreads();
    }
    if (t < nb) o[t] = s[t] - orig;
    if (t == 0) o[nb] = E;
}

__launch_bounds__(256)
__global__ void part_scatter(const int* __restrict__ nd, const int* __restrict__ he,
                             const int* __restrict__ coffN, const int* __restrict__ coffM,
                             int* __restrict__ gcurN, int* __restrict__ gcurM,
                             unsigned int* __restrict__ stN, unsigned int* __restrict__ stM,
                             int E) {
    __shared__ int hN[256], hM[256];
    const int t = threadIdx.x;
    hN[t] = 0; hM[t] = 0;
    __syncthreads();
    const int base = blockIdx.x * 4096;
    for (int i = t; i < 4096; i += 256) {
        int e = base + i;
        if (e < E) {
            atomicAdd(&hN[nd[e] >> SH_N], 1);
            atomicAdd(&hM[he[e] >> SH_M], 1);
        }
    }
    __syncthreads();
    int cN = hN[t], cM = hM[t];
    __syncthreads();
    if (cN) hN[t] = coffN[t] + atomicAdd(&gcurN[t], cN);
    if (cM) hM[t] = coffM[t] + atomicAdd(&gcurM[t], cM);
    __syncthreads();
    for (int i = t; i < 4096; i += 256) {
        int e = base + i;
        if (e < E) {
            int d = nd[e], h = he[e];
            int pN = atomicAdd(&hN[d >> SH_N], 1);
            stN[pN] = ((unsigned int)(d & 511) << 14) | (unsigned int)h;
            int pM = atomicAdd(&hM[h >> SH_M], 1);
            stM[pM] = ((unsigned int)(h & 63) << 17) | (unsigned int)d;
        }
    }
}

__launch_bounds__(256)
__global__ void bucket_build(const unsigned int* __restrict__ stN,
                             const unsigned int* __restrict__ stM,
                             const int* __restrict__ coffN, const int* __restrict__ coffM,
                             int* __restrict__ nd_off, int* __restrict__ he_off,
                             int* __restrict__ nd_adj, int* __restrict__ he_adj) {
    __shared__ int cnt[512];
    __shared__ int cur[512];
    __shared__ int ps[256];
    int b = blockIdx.x;
    const int t = threadIdx.x;
    const unsigned int* st; const int* coff; int* offout; int* adj;
    int dmin, dcnt2, sshift; unsigned int smask; int ntot;
    if (b < NB_N) {
        st = stN; coff = coffN; offout = nd_off; adj = nd_adj;
        dmin = b << SH_N; dcnt2 = min(512, HY_N - dmin);
        sshift = 14; smask = 0x3FFFu; ntot = HY_N;
    } else {
        b -= NB_N;
        st = stM; coff = coffM; offout = he_off; adj = he_adj;
        dmin = b << SH_M; dcnt2 = min(64, HY_M - dmin);
        sshift = 17; smask = 0x1FFFFu; ntot = HY_M;
    }
    const int cbase = coff[b], cend = coff[b + 1];
    cnt[t] = 0; cnt[t + 256] = 0;
    __syncthreads();
    for (int k = cbase + t; k < cend; k += 256)
        atomicAdd(&cnt[st[k] >> sshift], 1);
    __syncthreads();
    int a0 = cnt[2 * t], a1 = cnt[2 * t + 1];
    int pair = a0 + a1;
    ps[t] = pair;
    __syncthreads();
    for (int off = 1; off < 256; off <<= 1) {
        int x = (t >= off) ? ps[t - off] : 0;
        __syncthreads(); ps[t] += x; __syncthreads();
    }
    int excl = ps[t] - pair;
    cur[2 * t]     = cbase + excl;
    cur[2 * t + 1] = cbase + excl + a0;
    __syncthreads();
    for (int i = t; i < dcnt2; i += 256) offout[dmin + i] = cur[i];
    if (t == 0 && dmin + dcnt2 == ntot) offout[ntot] = cend;
    __syncthreads();
    for (int k = cbase + t; k < cend; k += 256) {
        unsigned int w = st[k];
        int pos = atomicAdd(&cur[w >> sshift], 1);
        adj[pos] = (int)(w & smask);
    }
}

// ---------------- degree-sorted node permutation ----------------
__global__ void deg_hist(const int* __restrict__ off, int* __restrict__ dcnt, int n) {
    __shared__ int h[64];
    int t = threadIdx.x;
    if (t < 64) h[t] = 0;
    __syncthreads();
    int i = blockIdx.x * blockDim.x + t;
    if (i < n) atomicAdd(&h[min(off[i + 1] - off[i], 63)], 1);
    __syncthreads();
    if (t < 64 && h[t]) atomicAdd(&dcnt[t], h[t]);
}

__global__ void deg_scan(const int* __restrict__ dcnt, int* __restrict__ dcur) {
    int t = threadIdx.x;   // 64 threads = 1 wave
    int v = dcnt[t];
    int s = v;
    for (int o = 1; o < 64; o <<= 1) {
        int x = __shfl_up(s, o, 64);
        if (t >= o) s += x;
    }
    dcur[t] = s - v;       // exclusive
}

__global__ void deg_scatter(const int* __restrict__ off, int* __restrict__ dcur,
                            int* __restrict__ nperm, int n) {
    int i = blockIdx.x * blockDim.x + threadIdx.x;
    if (i < n) {
        int p = atomicAdd(&dcur[min(off[i + 1] - off[i], 63)], 1);
        nperm[p] = i;
    }
}

// ---------------- f32 GEMM core for 128x128 weight products ----------------
__device__ __forceinline__ void gemm_accum(const float* __restrict__ A,
        const float* __restrict__ W, int nrows, float* wlds,
        float (&acc)[4][4], int row0) {
    const int tid = threadIdx.x;
    const int cg = tid & 31;
    for (int i = tid; i < 4096; i += 512)
        ((float4*)wlds)[i] = ((const float4*)W)[i];
    __syncthreads();
    const float4* A0 = (const float4*)(A + (size_t)min(row0 + 0, nrows - 1) * 128);
    const float4* A1 = (const float4*)(A + (size_t)min(row0 + 1, nrows - 1) * 128);
    const float4* A2 = (const float4*)(A + (size_t)min(row0 + 2, nrows - 1) * 128);
    const float4* A3 = (const float4*)(A + (size_t)min(row0 + 3, nrows - 1) * 128);
    #pragma unroll 2
    for (int kq = 0; kq < 32; ++kq) {
        float4 ar[4] = {A0[kq], A1[kq], A2[kq], A3[kq]};
        const float4* wk = (const float4*)(wlds + kq * 512);
        float4 wr[4] = {wk[cg], wk[32 + cg], wk[64 + cg], wk[96 + cg]};
        #pragma unroll
        for (int r = 0; r < 4; ++r) {
            float av[4] = {ar[r].x, ar[r].y, ar[r].z, ar[r].w};
            #pragma unroll
            for (int j = 0; j < 4; ++j) {
                float wv[4] = {wr[j].x, wr[j].y, wr[j].z, wr[j].w};
                #pragma unroll
                for (int c = 0; c < 4; ++c)
                    acc[r][c] = fmaf(av[j], wv[c], acc[r][c]);
            }
        }
    }
}

__device__ __forceinline__ void gemm_store_f32(const float* __restrict__ b,
        float* __restrict__ Cf, int nrows, float (&acc)[4][4], int row0) {
    const int cg = threadIdx.x & 31;
    const float4 bv = ((const float4*)b)[cg];
    #pragma unroll
    for (int r = 0; r < 4; ++r) {
        int gr = row0 + r;
        if (gr < nrows) {
            float4 o = {acc[r][0] + bv.x, acc[r][1] + bv.y,
                        acc[r][2] + bv.z, acc[r][3] + bv.w};
            ((float4*)(Cf + (size_t)gr * 128))[cg] = o;
        }
    }
}

// y=0: W12=W1@W2T ; y=1: W54=W5@W4T
__launch_bounds__(512)
__global__ void gemm_pair(const float* __restrict__ Aa, const float* __restrict__ Wa,
                          float* __restrict__ Ca,
                          const float* __restrict__ Ab, const float* __restrict__ Wb,
                          float* __restrict__ Cb2, const float* __restrict__ zb) {
    __shared__ __align__(16) float wlds[16384];
    const int rs = threadIdx.x >> 5;
    const int row0 = blockIdx.x * 64 + rs * 4;
    const float* A = blockIdx.y ? Ab : Aa;
    const float* W = blockIdx.y ? Wb : Wa;
    float* C = blockIdx.y ? Cb2 : Ca;
    float acc[4][4] = {};
    gemm_accum(A, W, 128, wlds, acc, row0);
    gemm_store_f32(zb, C, 128, acc, row0);
}

// y=0: Wk=Wfl@W54 ; y=1: Wv=Wfl@W6 ; y=2: Wq=Wfl@W12
__launch_bounds__(512)
__global__ void gemm_trip(const float* __restrict__ Wfl,
        const float* __restrict__ W54, const float* __restrict__ W6,
        const float* __restrict__ W12, float* __restrict__ Wk,
        float* __restrict__ Wv, float* __restrict__ Wq, const float* __restrict__ zb) {
    __shared__ __align__(16) float wlds[16384];
    const int rs = threadIdx.x >> 5;
    const int row0 = blockIdx.x * 64 + rs * 4;
    const float* W = blockIdx.y == 0 ? W54 : (blockIdx.y == 1 ? W6 : W12);
    float* C = blockIdx.y == 0 ? Wk : (blockIdx.y == 1 ? Wv : Wq);
    float acc[4][4] = {};
    gemm_accum(Wfl, W, 128, wlds, acc, row0);
    gemm_store_f32(zb, C, 128, acc, row0);
}

// ---------------- main M-row batched GEMM: efeat -> kv table + qt_e ----------
// 32 rows x 64 cols per block, 256 threads, 32KB LDS (half-W).
// blockIdx.y: mat = y>>1 (0=kt,1=v,2=qt), half = y&1 (column half).
__launch_bounds__(256)
__global__ void gemm_m(const float* __restrict__ A,
        const float* __restrict__ Wk, const float* __restrict__ bk,
        const float* __restrict__ Wv, const float* __restrict__ bvv,
        const float* __restrict__ Wq, const float* __restrict__ bq,
        unsigned short* __restrict__ kv, float* __restrict__ qt, int nrows) {
    __shared__ __align__(16) float wlds[128 * 64];
    const int tid = threadIdx.x;
    const int mat = blockIdx.y >> 1;
    const int half = blockIdx.y & 1;
    const float* W = mat == 0 ? Wk : (mat == 1 ? Wv : Wq);
    const float* bb = mat == 0 ? bk : (mat == 1 ? bvv : bq);
    const float4* W4 = (const float4*)W;
    float4* wl4 = (float4*)wlds;
    for (int i = tid; i < 2048; i += 256)
        wl4[i] = W4[(i >> 4) * 32 + half * 16 + (i & 15)];
    __syncthreads();
    const int cg = tid & 15;              // cols 4cg..4cg+3 (within half)
    const int rs = tid >> 4;              // rows 2rs, 2rs+1
    const int row0 = blockIdx.x * 32 + rs * 2;
    const float4* A0 = (const float4*)(A + (size_t)min(row0, nrows - 1) * 128);
    const float4* A1 = (const float4*)(A + (size_t)min(row0 + 1, nrows - 1) * 128);
    float acc[2][4] = {};
    #pragma unroll 4
    for (int kq = 0; kq < 32; ++kq) {
        float4 a0 = A0[kq], a1 = A1[kq];
        float av0[4] = {a0.x, a0.y, a0.z, a0.w};
        float av1[4] = {a1.x, a1.y, a1.z, a1.w};
        #pragma unroll
        for (int jj = 0; jj < 4; ++jj) {
            float4 w4 = wl4[(4 * kq + jj) * 16 + cg];
            float wv4[4] = {w4.x, w4.y, w4.z, w4.w};
            #pragma unroll
            for (int c = 0; c < 4; ++c) {
                acc[0][c] = fmaf(av0[jj], wv4[c], acc[0][c]);
                acc[1][c] = fmaf(av1[jj], wv4[c], acc[1][c]);
            }
        }
    }
    const float4 bv4 = ((const float4*)bb)[half * 16 + cg];
    #pragma unroll
    for (int r = 0; r < 2; ++r) {
        int gr = row0 + r;
        if (gr < nrows) {
            float o0 = acc[r][0] + bv4.x, o1 = acc[r][1] + bv4.y;
            float o2 = acc[r][2] + bv4.z, o3 = acc[r][3] + bv4.w;
            if (mat == 2) {
                float4 o = {o0, o1, o2, o3};
                ((float4*)(qt + (size_t)gr * 128))[half * 16 + cg] = o;
            } else {
                uint2 pk;
                pk.x = f2bf(o0) | (f2bf(o1) << 16);
                pk.y = f2bf(o2) | (f2bf(o3) << 16);
                *(uint2*)(kv + (size_t)gr * 256 + mat * 128 + half * 64 + cg * 4) = pk;
            }
        }
    }
}

// ---------------- tiny precompute kernels ----------------
__global__ void transpose2(const float* __restrict__ W2, const float* __restrict__ W4,
                           float* __restrict__ W2T, float* __restrict__ W4T) {
    int i = blockIdx.x * 256 + threadIdx.x;
    const float* s = blockIdx.y ? W4 : W2;
    float* d = blockIdx.y ? W4T : W2T;
    if (i < 128 * 128) d[(i & 127) * 128 + (i >> 7)] = s[i];
}

// bXY = WY@bX ; wXbY = WX@bY ; sXY = bX.bY
__global__ void prep_vecs(const float* __restrict__ WX, const float* __restrict__ WY,
                          const float* __restrict__ bX, const float* __restrict__ bY,
                          float* __restrict__ bXY, float* __restrict__ wXbY,
                          float* __restrict__ sXY) {
    int t = threadIdx.x;  // 256
    if (t < 128) {
        float acc = 0.f;
        for (int j = 0; j < 128; ++j) acc += WY[t * 128 + j] * bX[j];
        bXY[t] = acc;
    } else {
        int k = t - 128;
        float acc = 0.f;
        for (int j = 0; j < 128; ++j) acc += WX[k * 128 + j] * bY[j];
        wXbY[k] = acc;
    }
    if (t == 0) {
        float acc = 0.f;
        for (int j = 0; j < 128; ++j) acc += bX[j] * bY[j];
        *sXY = acc;
    }
}

// fold bfl/Wfl: bk=bfl@W54+b54v ; bv=bfl@W6+b6 ; bq=bfl@W12+b12v ;
// u_c=Wfl@w1b2 ; u_k=Wfl@w5b4 ; t_c=bfl.w1b2+s12 ; t_k=bfl.w5b4+s54
__global__ void prep_fold(const float* __restrict__ Wfl, const float* __restrict__ bfl,
                          const float* __restrict__ W54, const float* __restrict__ b54v,
                          const float* __restrict__ W6, const float* __restrict__ b6,
                          const float* __restrict__ W12, const float* __restrict__ b12v,
                          const float* __restrict__ w1b2, const float* __restrict__ s12,
                          const float* __restrict__ w5b4, const float* __restrict__ s54,
                          float* __restrict__ bk, float* __restrict__ bv,
                          float* __restrict__ bq, float* __restrict__ u_c,
                          float* __restrict__ u_k, float* __restrict__ t_c,
                          float* __restrict__ t_k) {
    int t = threadIdx.x;  // 256
    if (t < 128) {
        float a1 = 0.f, a2 = 0.f, a3 = 0.f;
        for (int j = 0; j < 128; ++j) {
            float f = bfl[j];
            a1 += f * W54[j * 128 + t];
            a2 += f * W6[j * 128 + t];
            a3 += f * W12[j * 128 + t];
        }
        bk[t] = a1 + b54v[t];
        bv[t] = a2 + b6[t];
        bq[t] = a3 + b12v[t];
    } else {
        int k = t - 128;
        float a1 = 0.f, a2 = 0.f;
        for (int j = 0; j < 128; ++j) {
            float f = Wfl[k * 128 + j];
            a1 += f * w1b2[j];
            a2 += f * w5b4[j];
        }
        u_c[k] = a1;
        u_k[k] = a2;
    }
    if (t == 0) {
        float a1 = 0.f, a2 = 0.f;
        for (int j = 0; j < 128; ++j) { a1 += bfl[j] * w1b2[j]; a2 += bfl[j] * w5b4[j]; }
        *t_c = a1 + *s12;
        *t_k = a2 + *s54;
    }
}

__global__ void prep_w3c(const float* __restrict__ W3, const float* __restrict__ Wc,
                         const float* __restrict__ b3, float* __restrict__ W3c,
                         float* __restrict__ b3c) {
    int i = blockIdx.x * 256 + threadIdx.x;
    if (i < 1280) {
        int k = i / 10, c = i % 10;
        float acc = 0.f;
        for (int j = 0; j < 128; ++j) acc += W3[k * 128 + j] * Wc[j * 10 + c];
        W3c[i] = acc;
    } else if (i < 1290) {
        int c = i - 1280;
        float acc = 0.f;
        for (int j = 0; j < 128; ++j) acc += b3[j] * Wc[j * 10 + c];
        b3c[c] = acc;
    }
}

// two dots per efeat row: c_e = X.u1 + t1 ; ck = X.u2 + t2
__launch_bounds__(256)
__global__ void dotc2(const float* __restrict__ X,
                      const float* __restrict__ u1, const float* __restrict__ t1v,
                      const float* __restrict__ u2, const float* __restrict__ t2v,
                      float* __restrict__ o1, float* __restrict__ o2, int M) {
    int w = (blockIdx.x * blockDim.x + threadIdx.x) >> 6;
    int lane = threadIdx.x & 63;
    if (w >= M) return;
    float2 r = ((const float2*)(X + (size_t)w * 128))[lane];
    float2 a1 = ((const float2*)u1)[lane];
    float2 a2 = ((const float2*)u2)[lane];
    float d1 = r.x * a1.x + r.y * a1.y;
    float d2 = r.x * a2.x + r.y * a2.y;
    #pragma unroll
    for (int o = 32; o; o >>= 1) {
        d1 += __shfl_xor(d1, o, 64);
        d2 += __shfl_xor(d2, o, 64);
    }
    if (lane == 0) { o1[w] = d1 + *t1v; o2[w] = d2 + *t2v; }
}

// ---------------- stage 1: hyperedge -> node (degree-sorted schedule) --------
__launch_bounds__(256)
__global__ void attn_s1(const float* __restrict__ vf,          // N x 128 f32
                        const unsigned int* __restrict__ kv,   // M x 128 words (kt|v)
                        const float* __restrict__ ck,          // M
                        const int* __restrict__ off, const int* __restrict__ adj,
                        const int* __restrict__ nperm,
                        unsigned int* __restrict__ fv,         // N x 64 words
                        int nseg, float scale) {
    int slot = (blockIdx.x * blockDim.x + threadIdx.x) >> 4;
    int j = threadIdx.x & 15;
    if (slot >= nseg) return;
    int seg = nperm[slot];
    int beg = off[seg], end = off[seg + 1];
    const float4 qa = ((const float4*)(vf + (size_t)seg * 128 + 8 * j))[0];
    const float4 qb = ((const float4*)(vf + (size_t)seg * 128 + 8 * j))[1];
    float m = -INFINITY, l = 0.f;
    float a[8] = {};
    if (beg < end) {
        int s = adj[beg];
        uint4 kw = ((const uint4*)(kv + (size_t)s * 128))[j];
        uint4 vw = ((const uint4*)(kv + (size_t)s * 128 + 64))[j];
        float ckn = ck[s];
        for (int i = beg; i < end; ++i) {
            uint4 kc = kw, vc = vw;
            float ckc = ckn;
            if (i + 1 < end) {
                int s2 = adj[i + 1];
                kw = ((const uint4*)(kv + (size_t)s2 * 128))[j];
                vw = ((const uint4*)(kv + (size_t)s2 * 128 + 64))[j];
                ckn = ck[s2];
            }
            float2 k0 = bf2x2(kc.x), k1 = bf2x2(kc.y), k2 = bf2x2(kc.z), k3 = bf2x2(kc.w);
            float d = k0.x * qa.x + k0.y * qa.y + k1.x * qa.z + k1.y * qa.w
                    + k2.x * qb.x + k2.y * qb.y + k3.x * qb.z + k3.y * qb.w;
            d += __shfl_xor(d, 8); d += __shfl_xor(d, 4);
            d += __shfl_xor(d, 2); d += __shfl_xor(d, 1);
            d += ckc;
            d = (d >= 0.f ? d : 0.01f * d) * scale;
            float2 v0 = bf2x2(vc.x), v1 = bf2x2(vc.y), v2 = bf2x2(vc.z), v3 = bf2x2(vc.w);
            float vfv[8] = {v0.x, v0.y, v1.x, v1.y, v2.x, v2.y, v3.x, v3.y};
            float mn = fmaxf(m, d);
            float r = __expf(m - mn);
            float p = __expf(d - mn);
            l = l * r + p;
            #pragma unroll
            for (int t = 0; t < 8; ++t) a[t] = a[t] * r + p * vfv[t];
            m = mn;
        }
    }
    float inv = (l > 0.f) ? 1.f / l : 0.f;
    uint4 o;
    o.x = f2bf(a[0] * inv) | (f2bf(a[1] * inv) << 16);
    o.y = f2bf(a[2] * inv) | (f2bf(a[3] * inv) << 16);
    o.z = f2bf(a[4] * inv) | (f2bf(a[5] * inv) << 16);
    o.w = f2bf(a[6] * inv) | (f2bf(a[7] * inv) << 16);
    ((uint4*)(fv + (size_t)seg * 64))[j] = o;
}

// ---------------- stage 2: node -> hyperedge --------------------------------
__launch_bounds__(256)
__global__ void attn_s2(const float* __restrict__ QT, const float* __restrict__ cvec,
                        const unsigned int* __restrict__ fv,
                        const int* __restrict__ off, const int* __restrict__ adj,
                        float* __restrict__ agg, float* __restrict__ flag, float scale) {
    __shared__ float sm[16], sl[16];
    __shared__ float sacc[16][16][9];
    const int seg = blockIdx.x;
    const int g = threadIdx.x >> 4;
    const int j = threadIdx.x & 15;
    const int beg = off[seg], end = off[seg + 1];
    const float4 qa = ((const float4*)(QT + (size_t)seg * 128 + 8 * j))[0];
    const float4 qb = ((const float4*)(QT + (size_t)seg * 128 + 8 * j))[1];
    const float cadd = cvec[seg];
    float m = -INFINITY, l = 0.f;
    float a[8] = {};
    int i = beg + g;
    if (i < end) {
        int s = adj[i];
        uint4 rw = ((const uint4*)(fv + (size_t)s * 64))[j];
        for (; i < end; i += 16) {
            uint4 rc = rw;
            if (i + 16 < end) {
                int s2 = adj[i + 16];
                rw = ((const uint4*)(fv + (size_t)s2 * 64))[j];
            }
            float2 r0 = bf2x2(rc.x), r1 = bf2x2(rc.y), r2 = bf2x2(rc.z), r3 = bf2x2(rc.w);
            float rf[8] = {r0.x, r0.y, r1.x, r1.y, r2.x, r2.y, r3.x, r3.y};
            float d = rf[0] * qa.x + rf[1] * qa.y + rf[2] * qa.z + rf[3] * qa.w
                    + rf[4] * qb.x + rf[5] * qb.y + rf[6] * qb.z + rf[7] * qb.w;
            d += __shfl_xor(d, 8); d += __shfl_xor(d, 4);
            d += __shfl_xor(d, 2); d += __shfl_xor(d, 1);
            d += cadd;
            d = (d >= 0.f ? d : 0.01f * d) * scale;
            float mn = fmaxf(m, d);
            float r = __expf(m - mn);
            float p = __expf(d - mn);
            l = l * r + p;
            #pragma unroll
            for (int t = 0; t < 8; ++t) a[t] = a[t] * r + p * rf[t];
            m = mn;
        }
    }
    if (j == 0) { sm[g] = m; sl[g] = l; }
    #pragma unroll
    for (int t = 0; t < 8; ++t) sacc[g][j][t] = a[t];
    __syncthreads();
    if (threadIdx.x < 16) {
        float M2 = -INFINITY;
        #pragma unroll 4
        for (int gg = 0; gg < 16; ++gg) if (sl[gg] > 0.f) M2 = fmaxf(M2, sm[gg]);
        float L = 0.f;
        float acc[8] = {};
        #pragma unroll 4
        for (int gg = 0; gg < 16; ++gg) {
            float f = (sl[gg] > 0.f) ? __expf(sm[gg] - M2) : 0.f;
            L += f * sl[gg];
            #pragma unroll
            for (int t = 0; t < 8; ++t) acc[t] += f * sacc[gg][threadIdx.x][t];
        }
        float inv = (L > 0.f) ? 1.f / L : 0.f;
        float4 o1 = {acc[0] * inv, acc[1] * inv, acc[2] * inv, acc[3] * inv};
        float4 o2 = {acc[4] * inv, acc[5] * inv, acc[6] * inv, acc[7] * inv};
        ((float4*)(agg + (size_t)seg * 128 + 8 * threadIdx.x))[0] = o1;
        ((float4*)(agg + (size_t)seg * 128 + 8 * threadIdx.x))[1] = o2;
        if (threadIdx.x == 0) flag[seg] = (L > 0.f) ? 1.f : 0.f;
    }
}

// pred[m,c] = agg[m].W3c[:,c] + flag[m]*b3c[c] + bc[c]
__global__ void head2(const float* __restrict__ agg, const float* __restrict__ flag,
                      const float* __restrict__ W3c, const float* __restrict__ b3c,
                      const float* __restrict__ bc, float* __restrict__ out, int M) {
    int t = blockIdx.x * blockDim.x + threadIdx.x;
    if (t >= M * 10) return;
    int row = t / 10, c = t % 10;
    float acc = bc[c] + flag[row] * b3c[c];
    #pragma unroll 8
    for (int k = 0; k < 128; ++k)
        acc = fmaf(agg[(size_t)row * 128 + k], W3c[k * 10 + c], acc);
    out[t] = acc;
}

extern "C" void kernel_launch(void* const* d_in, const int* in_sizes, int n_in,
                              void* d_out, int out_size, void* d_ws, size_t ws_size,
                              hipStream_t stream) {
    const float* vfeat = (const float*)d_in[0];
    const float* efeat = (const float*)d_in[1];
    const int*   he    = (const int*)d_in[2];
    const int*   nd    = (const int*)d_in[3];
    const float* Wfl = (const float*)d_in[6],  *bfl = (const float*)d_in[7];
    const float* W1  = (const float*)d_in[8],  *b1  = (const float*)d_in[9];
    const float* W2  = (const float*)d_in[10], *b2  = (const float*)d_in[11];
    const float* W3  = (const float*)d_in[12], *b3  = (const float*)d_in[13];
    const float* W4  = (const float*)d_in[14], *b4  = (const float*)d_in[15];
    const float* W5  = (const float*)d_in[16], *b5  = (const float*)d_in[17];
    const float* W6  = (const float*)d_in[18], *b6  = (const float*)d_in[19];
    const float* Wc  = (const float*)d_in[20], *bc  = (const float*)d_in[21];
    float* out = (float*)d_out;
    float* ws  = (float*)d_ws;

    const int M = HY_M, N = HY_N, E = HY_E;

    // -------- workspace layout (float units) --------
    float* qt_e  = ws + 0;         // 1,280,000
    float* agg   = ws + 1280000;   // 1,280,000
    float* c_e   = ws + 2560000;   // 10,000
    float* ck    = ws + 2570000;   // 10,000
    float* flag  = ws + 2580000;   // 10,000
    float* W2T   = ws + 2590000;   // 16384
    float* W4T   = ws + 2606384;   // 16384
    float* W12   = ws + 2622768;   // 16384
    float* W54   = ws + 2639152;   // 16384
    float* Wk    = ws + 2655536;   // 16384
    float* Wv    = ws + 2671920;   // 16384
    float* Wq    = ws + 2688304;   // 16384
    float* W3c   = ws + 2704688;   // 1280
    float* b3c   = ws + 2705968;   // 16
    float* b12v  = ws + 2705984;   // 128
    float* w1b2  = ws + 2706112;   // 128
    float* s12   = ws + 2706240;   // 4
    float* b54v  = ws + 2706244;   // 128
    float* w5b4  = ws + 2706372;   // 128
    float* s54   = ws + 2706500;   // 4
    float* bk    = ws + 2706504;   // 128
    float* bv    = ws + 2706632;   // 128
    float* bq    = ws + 2706760;   // 128
    float* u_c   = ws + 2706888;   // 128
    float* u_k   = ws + 2707016;   // 128
    float* t_c   = ws + 2707144;   // 4
    float* t_k   = ws + 2707148;   // 4
    float* zeros = ws + 2707152;   // 128
    unsigned int* kv_bf = (unsigned int*)(ws + 2707280);   // M*128 = 1,280,000 words
    unsigned int* fv_bf = kv_bf + (size_t)M * 128;         // N*64 = 6,400,000 words
    int* nd_off = (int*)(fv_bf + (size_t)N * 64);          // 100,001
    int* he_off = nd_off + 100001;                          // 10,001
    int* nd_adj = he_off + 10001;                           // 640,000
    int* he_adj = nd_adj + 640000;                          // 640,000
    int* nperm  = he_adj + 640000;                          // 100,000
    unsigned int* stN = (unsigned int*)(nperm + 100000);    // 640,000
    unsigned int* stM = stN + 640000;                       // 640,000
    int* gcntN = (int*)(stM + 640000);                      // 256
    int* gcntM = gcntN + 256;                               // 256
    int* gcurN = gcntM + 256;                               // 256
    int* gcurM = gcurN + 256;                               // 256
    int* dcnt  = gcurM + 256;                               // 64
    int* dcur  = dcnt + 64;                                 // 64
    int* coffN = dcur + 64;                                 // 256 (197 used)
    int* coffM = coffN + 256;                               // 256 (158 used)

    const float scale = 0.08838834764831843f;  // 1/sqrt(128)
    const int nchunk = (E + 4095) / 4096;      // 157

    // -------- CSR build (both orientations) --------
    zero_ints<<<5, 256, 0, stream>>>(gcntN, 1152);   // gcnt/gcur + dcnt/dcur
    coarse_hist<<<nchunk, 256, 0, stream>>>(nd, he, gcntN, gcntM, E);
    coarse_scan<<<2, 256, 0, stream>>>(gcntN, gcntM, coffN, coffM, E);
    part_scatter<<<nchunk, 256, 0, stream>>>(nd, he, coffN, coffM,
                                             gcurN, gcurM, stN, stM, E);
    bucket_build<<<NB_N + NB_M, 256, 0, stream>>>(stN, stM, coffN, coffM,
                                                  nd_off, he_off, nd_adj, he_adj);

    // -------- degree-sorted node permutation --------
    deg_hist<<<(N + 255) / 256, 256, 0, stream>>>(nd_off, dcnt, N);
    deg_scan<<<1, 64, 0, stream>>>(dcnt, dcur);
    deg_scatter<<<(N + 255) / 256, 256, 0, stream>>>(nd_off, dcur, nperm, N);

    // -------- weight precomputes --------
    transpose2<<<dim3(64, 2), 256, 0, stream>>>(W2, W4, W2T, W4T);
    fillk<<<1, 128, 0, stream>>>(zeros, 0.f, 128);
    prep_vecs<<<1, 256, 0, stream>>>(W1, W2, b1, b2, b12v, w1b2, s12);
    prep_vecs<<<1, 256, 0, stream>>>(W5, W4, b5, b4, b54v, w5b4, s54);
    gemm_pair<<<dim3(2, 2), 512, 0, stream>>>(W1, W2T, W12, W5, W4T, W54, zeros);
    gemm_trip<<<dim3(2, 3), 512, 0, stream>>>(Wfl, W54, W6, W12, Wk, Wv, Wq, zeros);
    prep_fold<<<1, 256, 0, stream>>>(Wfl, bfl, W54, b54v, W6, b6, W12, b12v,
                                     w1b2, s12, w5b4, s54,
                                     bk, bv, bq, u_c, u_k, t_c, t_k);
    prep_w3c<<<6, 256, 0, stream>>>(W3, Wc, b3, W3c, b3c);

    // -------- M-row dense layer (single batched GEMM over efeat) --------
    gemm_m<<<dim3((M + 31) / 32, 6), 256, 0, stream>>>(
        efeat, Wk, bk, Wv, bv, Wq, bq, (unsigned short*)kv_bf, qt_e, M);
    dotc2<<<(M * 64 + 255) / 256, 256, 0, stream>>>(efeat, u_c, t_c, u_k, t_k,
                                                    c_e, ck, M);

    // -------- stage 1: hyperedge -> node --------
    attn_s1<<<(N * 16 + 255) / 256, 256, 0, stream>>>(
        vfeat, kv_bf, ck, nd_off, nd_adj, nperm, fv_bf, N, scale);

    // -------- stage 2: node -> hyperedge --------
    attn_s2<<<M, 256, 0, stream>>>(qt_e, c_e, fv_bf, he_off, he_adj, agg, flag, scale);

    // -------- head --------
    head2<<<(M * 10 + 255) / 256, 256, 0, stream>>>(agg, flag, W3c, b3c, bc, out, M);
}

// Round 10
// 245.908 us; speedup vs baseline: 2.4333x; 2.4333x over previous
//
#include <hip/hip_runtime.h>
#include <hip/hip_bf16.h>
#include <math.h>

// ---------------------------------------------------------------------------
// Seq_HyGAN round 10: fix deg_scatter atomic contention.
//  Round 9's deg_scatter did 100K atomicAdds into 64 global counters
//  (~15K serialized round-trips on hot bins -> 359us). Replaced with the
//  hierarchical pattern used everywhere else: LDS block-local histogram ->
//  one global reservation per (block,bin) -> block-local scatter.
//  Everything else unchanged from round 9.
// ---------------------------------------------------------------------------

#define HY_M 10000
#define HY_N 100000
#define HY_E 640000

#define SH_N 9              // node bucket width 512
#define NB_N 196            // ceil(100000/512)
#define SH_M 6              // hedge bucket width 64
#define NB_M 157            // ceil(10000/64)

// ---- bf16 helpers (manual, RN) ----
__device__ __forceinline__ unsigned int f2bf(float x) {
    unsigned int u = __float_as_uint(x);
    return (u + 0x7fffu + ((u >> 16) & 1u)) >> 16;
}
__device__ __forceinline__ float2 bf2x2(unsigned int w) {
    float lo = __uint_as_float(w << 16);
    float hi = __uint_as_float(w & 0xffff0000u);
    return make_float2(lo, hi);
}

// ---------------- small utility kernels ----------------
__global__ void zero_ints(int* __restrict__ p, int n) {
    int i = blockIdx.x * blockDim.x + threadIdx.x;
    if (i < n) p[i] = 0;
}

__global__ void fillk(float* __restrict__ p, float v, int n) {
    int stride = gridDim.x * blockDim.x;
    for (int i = blockIdx.x * blockDim.x + threadIdx.x; i < n; i += stride) p[i] = v;
}

// ---------------- CSR build: bucketed counting sort ----------------
__launch_bounds__(256)
__global__ void coarse_hist(const int* __restrict__ nd, const int* __restrict__ he,
                            int* __restrict__ gcntN, int* __restrict__ gcntM, int E) {
    __shared__ int hN[256], hM[256];
    const int t = threadIdx.x;
    hN[t] = 0; hM[t] = 0;
    __syncthreads();
    const int base = blockIdx.x * 4096;
    for (int i = t; i < 4096; i += 256) {
        int e = base + i;
        if (e < E) {
            atomicAdd(&hN[nd[e] >> SH_N], 1);
            atomicAdd(&hM[he[e] >> SH_M], 1);
        }
    }
    __syncthreads();
    if (hN[t]) atomicAdd(&gcntN[t], hN[t]);
    if (hM[t]) atomicAdd(&gcntM[t], hM[t]);
}

__global__ void coarse_scan(const int* __restrict__ gcntN, const int* __restrict__ gcntM,
                            int* __restrict__ coffN, int* __restrict__ coffM, int E) {
    __shared__ int s[256];
    const int* g = blockIdx.x ? gcntM : gcntN;
    int* o = blockIdx.x ? coffM : coffN;
    const int nb = blockIdx.x ? NB_M : NB_N;
    const int t = threadIdx.x;
    int v = (t < nb) ? g[t] : 0;
    int orig = v;
    s[t] = v; __syncthreads();
    for (int off = 1; off < 256; off <<= 1) {
        int x = (t >= off) ? s[t - off] : 0;
        __syncthreads(); s[t] += x; __syncthreads();
    }
    if (t < nb) o[t] = s[t] - orig;
    if (t == 0) o[nb] = E;
}

__launch_bounds__(256)
__global__ void part_scatter(const int* __restrict__ nd, const int* __restrict__ he,
                             const int* __restrict__ coffN, const int* __restrict__ coffM,
                             int* __restrict__ gcurN, int* __restrict__ gcurM,
                             unsigned int* __restrict__ stN, unsigned int* __restrict__ stM,
                             int E) {
    __shared__ int hN[256], hM[256];
    const int t = threadIdx.x;
    hN[t] = 0; hM[t] = 0;
    __syncthreads();
    const int base = blockIdx.x * 4096;
    for (int i = t; i < 4096; i += 256) {
        int e = base + i;
        if (e < E) {
            atomicAdd(&hN[nd[e] >> SH_N], 1);
            atomicAdd(&hM[he[e] >> SH_M], 1);
        }
    }
    __syncthreads();
    int cN = hN[t], cM = hM[t];
    __syncthreads();
    if (cN) hN[t] = coffN[t] + atomicAdd(&gcurN[t], cN);
    if (cM) hM[t] = coffM[t] + atomicAdd(&gcurM[t], cM);
    __syncthreads();
    for (int i = t; i < 4096; i += 256) {
        int e = base + i;
        if (e < E) {
            int d = nd[e], h = he[e];
            int pN = atomicAdd(&hN[d >> SH_N], 1);
            stN[pN] = ((unsigned int)(d & 511) << 14) | (unsigned int)h;
            int pM = atomicAdd(&hM[h >> SH_M], 1);
            stM[pM] = ((unsigned int)(h & 63) << 17) | (unsigned int)d;
        }
    }
}

__launch_bounds__(256)
__global__ void bucket_build(const unsigned int* __restrict__ stN,
                             const unsigned int* __restrict__ stM,
                             const int* __restrict__ coffN, const int* __restrict__ coffM,
                             int* __restrict__ nd_off, int* __restrict__ he_off,
                             int* __restrict__ nd_adj, int* __restrict__ he_adj) {
    __shared__ int cnt[512];
    __shared__ int cur[512];
    __shared__ int ps[256];
    int b = blockIdx.x;
    const int t = threadIdx.x;
    const unsigned int* st; const int* coff; int* offout; int* adj;
    int dmin, dcnt2, sshift; unsigned int smask; int ntot;
    if (b < NB_N) {
        st = stN; coff = coffN; offout = nd_off; adj = nd_adj;
        dmin = b << SH_N; dcnt2 = min(512, HY_N - dmin);
        sshift = 14; smask = 0x3FFFu; ntot = HY_N;
    } else {
        b -= NB_N;
        st = stM; coff = coffM; offout = he_off; adj = he_adj;
        dmin = b << SH_M; dcnt2 = min(64, HY_M - dmin);
        sshift = 17; smask = 0x1FFFFu; ntot = HY_M;
    }
    const int cbase = coff[b], cend = coff[b + 1];
    cnt[t] = 0; cnt[t + 256] = 0;
    __syncthreads();
    for (int k = cbase + t; k < cend; k += 256)
        atomicAdd(&cnt[st[k] >> sshift], 1);
    __syncthreads();
    int a0 = cnt[2 * t], a1 = cnt[2 * t + 1];
    int pair = a0 + a1;
    ps[t] = pair;
    __syncthreads();
    for (int off = 1; off < 256; off <<= 1) {
        int x = (t >= off) ? ps[t - off] : 0;
        __syncthreads(); ps[t] += x; __syncthreads();
    }
    int excl = ps[t] - pair;
    cur[2 * t]     = cbase + excl;
    cur[2 * t + 1] = cbase + excl + a0;
    __syncthreads();
    for (int i = t; i < dcnt2; i += 256) offout[dmin + i] = cur[i];
    if (t == 0 && dmin + dcnt2 == ntot) offout[ntot] = cend;
    __syncthreads();
    for (int k = cbase + t; k < cend; k += 256) {
        unsigned int w = st[k];
        int pos = atomicAdd(&cur[w >> sshift], 1);
        adj[pos] = (int)(w & smask);
    }
}

// ---------------- degree-sorted node permutation ----------------
__global__ void deg_hist(const int* __restrict__ off, int* __restrict__ dcnt, int n) {
    __shared__ int h[64];
    int t = threadIdx.x;
    if (t < 64) h[t] = 0;
    __syncthreads();
    int i = blockIdx.x * blockDim.x + t;
    if (i < n) atomicAdd(&h[min(off[i + 1] - off[i], 63)], 1);
    __syncthreads();
    if (t < 64 && h[t]) atomicAdd(&dcnt[t], h[t]);
}

__global__ void deg_scan(const int* __restrict__ dcnt, int* __restrict__ dcur) {
    int t = threadIdx.x;   // 64 threads = 1 wave
    int v = dcnt[t];
    int s = v;
    for (int o = 1; o < 64; o <<= 1) {
        int x = __shfl_up(s, o, 64);
        if (t >= o) s += x;
    }
    dcur[t] = s - v;       // exclusive
}

// hierarchical: LDS block hist -> 1 global reservation per (block,bin) ->
// block-local scatter. (round 9 version: 100K direct atomics on 64 addrs = 359us)
__launch_bounds__(256)
__global__ void deg_scatter(const int* __restrict__ off, int* __restrict__ dcur,
                            int* __restrict__ nperm, int n) {
    __shared__ int h[64];
    __shared__ int basev[64];
    int t = threadIdx.x;
    if (t < 64) h[t] = 0;
    __syncthreads();
    int i = blockIdx.x * blockDim.x + t;
    int bin = 0, lpos = 0;
    bool valid = i < n;
    if (valid) {
        bin = min(off[i + 1] - off[i], 63);
        lpos = atomicAdd(&h[bin], 1);
    }
    __syncthreads();
    if (t < 64 && h[t]) basev[t] = atomicAdd(&dcur[t], h[t]);
    __syncthreads();
    if (valid) nperm[basev[bin] + lpos] = i;
}

// ---------------- f32 GEMM core for 128x128 weight products ----------------
__device__ __forceinline__ void gemm_accum(const float* __restrict__ A,
        const float* __restrict__ W, int nrows, float* wlds,
        float (&acc)[4][4], int row0) {
    const int tid = threadIdx.x;
    const int cg = tid & 31;
    for (int i = tid; i < 4096; i += 512)
        ((float4*)wlds)[i] = ((const float4*)W)[i];
    __syncthreads();
    const float4* A0 = (const float4*)(A + (size_t)min(row0 + 0, nrows - 1) * 128);
    const float4* A1 = (const float4*)(A + (size_t)min(row0 + 1, nrows - 1) * 128);
    const float4* A2 = (const float4*)(A + (size_t)min(row0 + 2, nrows - 1) * 128);
    const float4* A3 = (const float4*)(A + (size_t)min(row0 + 3, nrows - 1) * 128);
    #pragma unroll 2
    for (int kq = 0; kq < 32; ++kq) {
        float4 ar[4] = {A0[kq], A1[kq], A2[kq], A3[kq]};
        const float4* wk = (const float4*)(wlds + kq * 512);
        float4 wr[4] = {wk[cg], wk[32 + cg], wk[64 + cg], wk[96 + cg]};
        #pragma unroll
        for (int r = 0; r < 4; ++r) {
            float av[4] = {ar[r].x, ar[r].y, ar[r].z, ar[r].w};
            #pragma unroll
            for (int j = 0; j < 4; ++j) {
                float wv[4] = {wr[j].x, wr[j].y, wr[j].z, wr[j].w};
                #pragma unroll
                for (int c = 0; c < 4; ++c)
                    acc[r][c] = fmaf(av[j], wv[c], acc[r][c]);
            }
        }
    }
}

__device__ __forceinline__ void gemm_store_f32(const float* __restrict__ b,
        float* __restrict__ Cf, int nrows, float (&acc)[4][4], int row0) {
    const int cg = threadIdx.x & 31;
    const float4 bv = ((const float4*)b)[cg];
    #pragma unroll
    for (int r = 0; r < 4; ++r) {
        int gr = row0 + r;
        if (gr < nrows) {
            float4 o = {acc[r][0] + bv.x, acc[r][1] + bv.y,
                        acc[r][2] + bv.z, acc[r][3] + bv.w};
            ((float4*)(Cf + (size_t)gr * 128))[cg] = o;
        }
    }
}

// y=0: W12=W1@W2T ; y=1: W54=W5@W4T
__launch_bounds__(512)
__global__ void gemm_pair(const float* __restrict__ Aa, const float* __restrict__ Wa,
                          float* __restrict__ Ca,
                          const float* __restrict__ Ab, const float* __restrict__ Wb,
                          float* __restrict__ Cb2, const float* __restrict__ zb) {
    __shared__ __align__(16) float wlds[16384];
    const int rs = threadIdx.x >> 5;
    const int row0 = blockIdx.x * 64 + rs * 4;
    const float* A = blockIdx.y ? Ab : Aa;
    const float* W = blockIdx.y ? Wb : Wa;
    float* C = blockIdx.y ? Cb2 : Ca;
    float acc[4][4] = {};
    gemm_accum(A, W, 128, wlds, acc, row0);
    gemm_store_f32(zb, C, 128, acc, row0);
}

// y=0: Wk=Wfl@W54 ; y=1: Wv=Wfl@W6 ; y=2: Wq=Wfl@W12
__launch_bounds__(512)
__global__ void gemm_trip(const float* __restrict__ Wfl,
        const float* __restrict__ W54, const float* __restrict__ W6,
        const float* __restrict__ W12, float* __restrict__ Wk,
        float* __restrict__ Wv, float* __restrict__ Wq, const float* __restrict__ zb) {
    __shared__ __align__(16) float wlds[16384];
    const int rs = threadIdx.x >> 5;
    const int row0 = blockIdx.x * 64 + rs * 4;
    const float* W = blockIdx.y == 0 ? W54 : (blockIdx.y == 1 ? W6 : W12);
    float* C = blockIdx.y == 0 ? Wk : (blockIdx.y == 1 ? Wv : Wq);
    float acc[4][4] = {};
    gemm_accum(Wfl, W, 128, wlds, acc, row0);
    gemm_store_f32(zb, C, 128, acc, row0);
}

// ---------------- main M-row batched GEMM: efeat -> kv table + qt_e ----------
__launch_bounds__(256)
__global__ void gemm_m(const float* __restrict__ A,
        const float* __restrict__ Wk, const float* __restrict__ bk,
        const float* __restrict__ Wv, const float* __restrict__ bvv,
        const float* __restrict__ Wq, const float* __restrict__ bq,
        unsigned short* __restrict__ kv, float* __restrict__ qt, int nrows) {
    __shared__ __align__(16) float wlds[128 * 64];
    const int tid = threadIdx.x;
    const int mat = blockIdx.y >> 1;
    const int half = blockIdx.y & 1;
    const float* W = mat == 0 ? Wk : (mat == 1 ? Wv : Wq);
    const float* bb = mat == 0 ? bk : (mat == 1 ? bvv : bq);
    const float4* W4 = (const float4*)W;
    float4* wl4 = (float4*)wlds;
    for (int i = tid; i < 2048; i += 256)
        wl4[i] = W4[(i >> 4) * 32 + half * 16 + (i & 15)];
    __syncthreads();
    const int cg = tid & 15;
    const int rs = tid >> 4;
    const int row0 = blockIdx.x * 32 + rs * 2;
    const float4* A0 = (const float4*)(A + (size_t)min(row0, nrows - 1) * 128);
    const float4* A1 = (const float4*)(A + (size_t)min(row0 + 1, nrows - 1) * 128);
    float acc[2][4] = {};
    #pragma unroll 4
    for (int kq = 0; kq < 32; ++kq) {
        float4 a0 = A0[kq], a1 = A1[kq];
        float av0[4] = {a0.x, a0.y, a0.z, a0.w};
        float av1[4] = {a1.x, a1.y, a1.z, a1.w};
        #pragma unroll
        for (int jj = 0; jj < 4; ++jj) {
            float4 w4 = wl4[(4 * kq + jj) * 16 + cg];
            float wv4[4] = {w4.x, w4.y, w4.z, w4.w};
            #pragma unroll
            for (int c = 0; c < 4; ++c) {
                acc[0][c] = fmaf(av0[jj], wv4[c], acc[0][c]);
                acc[1][c] = fmaf(av1[jj], wv4[c], acc[1][c]);
            }
        }
    }
    const float4 bv4 = ((const float4*)bb)[half * 16 + cg];
    #pragma unroll
    for (int r = 0; r < 2; ++r) {
        int gr = row0 + r;
        if (gr < nrows) {
            float o0 = acc[r][0] + bv4.x, o1 = acc[r][1] + bv4.y;
            float o2 = acc[r][2] + bv4.z, o3 = acc[r][3] + bv4.w;
            if (mat == 2) {
                float4 o = {o0, o1, o2, o3};
                ((float4*)(qt + (size_t)gr * 128))[half * 16 + cg] = o;
            } else {
                uint2 pk;
                pk.x = f2bf(o0) | (f2bf(o1) << 16);
                pk.y = f2bf(o2) | (f2bf(o3) << 16);
                *(uint2*)(kv + (size_t)gr * 256 + mat * 128 + half * 64 + cg * 4) = pk;
            }
        }
    }
}

// ---------------- tiny precompute kernels ----------------
__global__ void transpose2(const float* __restrict__ W2, const float* __restrict__ W4,
                           float* __restrict__ W2T, float* __restrict__ W4T) {
    int i = blockIdx.x * 256 + threadIdx.x;
    const float* s = blockIdx.y ? W4 : W2;
    float* d = blockIdx.y ? W4T : W2T;
    if (i < 128 * 128) d[(i & 127) * 128 + (i >> 7)] = s[i];
}

__global__ void prep_vecs(const float* __restrict__ WX, const float* __restrict__ WY,
                          const float* __restrict__ bX, const float* __restrict__ bY,
                          float* __restrict__ bXY, float* __restrict__ wXbY,
                          float* __restrict__ sXY) {
    int t = threadIdx.x;  // 256
    if (t < 128) {
        float acc = 0.f;
        for (int j = 0; j < 128; ++j) acc += WY[t * 128 + j] * bX[j];
        bXY[t] = acc;
    } else {
        int k = t - 128;
        float acc = 0.f;
        for (int j = 0; j < 128; ++j) acc += WX[k * 128 + j] * bY[j];
        wXbY[k] = acc;
    }
    if (t == 0) {
        float acc = 0.f;
        for (int j = 0; j < 128; ++j) acc += bX[j] * bY[j];
        *sXY = acc;
    }
}

__global__ void prep_fold(const float* __restrict__ Wfl, const float* __restrict__ bfl,
                          const float* __restrict__ W54, const float* __restrict__ b54v,
                          const float* __restrict__ W6, const float* __restrict__ b6,
                          const float* __restrict__ W12, const float* __restrict__ b12v,
                          const float* __restrict__ w1b2, const float* __restrict__ s12,
                          const float* __restrict__ w5b4, const float* __restrict__ s54,
                          float* __restrict__ bk, float* __restrict__ bv,
                          float* __restrict__ bq, float* __restrict__ u_c,
                          float* __restrict__ u_k, float* __restrict__ t_c,
                          float* __restrict__ t_k) {
    int t = threadIdx.x;  // 256
    if (t < 128) {
        float a1 = 0.f, a2 = 0.f, a3 = 0.f;
        for (int j = 0; j < 128; ++j) {
            float f = bfl[j];
            a1 += f * W54[j * 128 + t];
            a2 += f * W6[j * 128 + t];
            a3 += f * W12[j * 128 + t];
        }
        bk[t] = a1 + b54v[t];
        bv[t] = a2 + b6[t];
        bq[t] = a3 + b12v[t];
    } else {
        int k = t - 128;
        float a1 = 0.f, a2 = 0.f;
        for (int j = 0; j < 128; ++j) {
            float f = Wfl[k * 128 + j];
            a1 += f * w1b2[j];
            a2 += f * w5b4[j];
        }
        u_c[k] = a1;
        u_k[k] = a2;
    }
    if (t == 0) {
        float a1 = 0.f, a2 = 0.f;
        for (int j = 0; j < 128; ++j) { a1 += bfl[j] * w1b2[j]; a2 += bfl[j] * w5b4[j]; }
        *t_c = a1 + *s12;
        *t_k = a2 + *s54;
    }
}

__global__ void prep_w3c(const float* __restrict__ W3, const float* __restrict__ Wc,
                         const float* __restrict__ b3, float* __restrict__ W3c,
                         float* __restrict__ b3c) {
    int i = blockIdx.x * 256 + threadIdx.x;
    if (i < 1280) {
        int k = i / 10, c = i % 10;
        float acc = 0.f;
        for (int j = 0; j < 128; ++j) acc += W3[k * 128 + j] * Wc[j * 10 + c];
        W3c[i] = acc;
    } else if (i < 1290) {
        int c = i - 1280;
        float acc = 0.f;
        for (int j = 0; j < 128; ++j) acc += b3[j] * Wc[j * 10 + c];
        b3c[c] = acc;
    }
}

__launch_bounds__(256)
__global__ void dotc2(const float* __restrict__ X,
                      const float* __restrict__ u1, const float* __restrict__ t1v,
                      const float* __restrict__ u2, const float* __restrict__ t2v,
                      float* __restrict__ o1, float* __restrict__ o2, int M) {
    int w = (blockIdx.x * blockDim.x + threadIdx.x) >> 6;
    int lane = threadIdx.x & 63;
    if (w >= M) return;
    float2 r = ((const float2*)(X + (size_t)w * 128))[lane];
    float2 a1 = ((const float2*)u1)[lane];
    float2 a2 = ((const float2*)u2)[lane];
    float d1 = r.x * a1.x + r.y * a1.y;
    float d2 = r.x * a2.x + r.y * a2.y;
    #pragma unroll
    for (int o = 32; o; o >>= 1) {
        d1 += __shfl_xor(d1, o, 64);
        d2 += __shfl_xor(d2, o, 64);
    }
    if (lane == 0) { o1[w] = d1 + *t1v; o2[w] = d2 + *t2v; }
}

// ---------------- stage 1: hyperedge -> node (degree-sorted schedule) --------
__launch_bounds__(256)
__global__ void attn_s1(const float* __restrict__ vf,          // N x 128 f32
                        const unsigned int* __restrict__ kv,   // M x 128 words (kt|v)
                        const float* __restrict__ ck,          // M
                        const int* __restrict__ off, const int* __restrict__ adj,
                        const int* __restrict__ nperm,
                        unsigned int* __restrict__ fv,         // N x 64 words
                        int nseg, float scale) {
    int slot = (blockIdx.x * blockDim.x + threadIdx.x) >> 4;
    int j = threadIdx.x & 15;
    if (slot >= nseg) return;
    int seg = nperm[slot];
    int beg = off[seg], end = off[seg + 1];
    const float4 qa = ((const float4*)(vf + (size_t)seg * 128 + 8 * j))[0];
    const float4 qb = ((const float4*)(vf + (size_t)seg * 128 + 8 * j))[1];
    float m = -INFINITY, l = 0.f;
    float a[8] = {};
    if (beg < end) {
        int s = adj[beg];
        uint4 kw = ((const uint4*)(kv + (size_t)s * 128))[j];
        uint4 vw = ((const uint4*)(kv + (size_t)s * 128 + 64))[j];
        float ckn = ck[s];
        for (int i = beg; i < end; ++i) {
            uint4 kc = kw, vc = vw;
            float ckc = ckn;
            if (i + 1 < end) {
                int s2 = adj[i + 1];
                kw = ((const uint4*)(kv + (size_t)s2 * 128))[j];
                vw = ((const uint4*)(kv + (size_t)s2 * 128 + 64))[j];
                ckn = ck[s2];
            }
            float2 k0 = bf2x2(kc.x), k1 = bf2x2(kc.y), k2 = bf2x2(kc.z), k3 = bf2x2(kc.w);
            float d = k0.x * qa.x + k0.y * qa.y + k1.x * qa.z + k1.y * qa.w
                    + k2.x * qb.x + k2.y * qb.y + k3.x * qb.z + k3.y * qb.w;
            d += __shfl_xor(d, 8); d += __shfl_xor(d, 4);
            d += __shfl_xor(d, 2); d += __shfl_xor(d, 1);
            d += ckc;
            d = (d >= 0.f ? d : 0.01f * d) * scale;
            float2 v0 = bf2x2(vc.x), v1 = bf2x2(vc.y), v2 = bf2x2(vc.z), v3 = bf2x2(vc.w);
            float vfv[8] = {v0.x, v0.y, v1.x, v1.y, v2.x, v2.y, v3.x, v3.y};
            float mn = fmaxf(m, d);
            float r = __expf(m - mn);
            float p = __expf(d - mn);
            l = l * r + p;
            #pragma unroll
            for (int t = 0; t < 8; ++t) a[t] = a[t] * r + p * vfv[t];
            m = mn;
        }
    }
    float inv = (l > 0.f) ? 1.f / l : 0.f;
    uint4 o;
    o.x = f2bf(a[0] * inv) | (f2bf(a[1] * inv) << 16);
    o.y = f2bf(a[2] * inv) | (f2bf(a[3] * inv) << 16);
    o.z = f2bf(a[4] * inv) | (f2bf(a[5] * inv) << 16);
    o.w = f2bf(a[6] * inv) | (f2bf(a[7] * inv) << 16);
    ((uint4*)(fv + (size_t)seg * 64))[j] = o;
}

// ---------------- stage 2: node -> hyperedge --------------------------------
__launch_bounds__(256)
__global__ void attn_s2(const float* __restrict__ QT, const float* __restrict__ cvec,
                        const unsigned int* __restrict__ fv,
                        const int* __restrict__ off, const int* __restrict__ adj,
                        float* __restrict__ agg, float* __restrict__ flag, float scale) {
    __shared__ float sm[16], sl[16];
    __shared__ float sacc[16][16][9];
    const int seg = blockIdx.x;
    const int g = threadIdx.x >> 4;
    const int j = threadIdx.x & 15;
    const int beg = off[seg], end = off[seg + 1];
    const float4 qa = ((const float4*)(QT + (size_t)seg * 128 + 8 * j))[0];
    const float4 qb = ((const float4*)(QT + (size_t)seg * 128 + 8 * j))[1];
    const float cadd = cvec[seg];
    float m = -INFINITY, l = 0.f;
    float a[8] = {};
    int i = beg + g;
    if (i < end) {
        int s = adj[i];
        uint4 rw = ((const uint4*)(fv + (size_t)s * 64))[j];
        for (; i < end; i += 16) {
            uint4 rc = rw;
            if (i + 16 < end) {
                int s2 = adj[i + 16];
                rw = ((const uint4*)(fv + (size_t)s2 * 64))[j];
            }
            float2 r0 = bf2x2(rc.x), r1 = bf2x2(rc.y), r2 = bf2x2(rc.z), r3 = bf2x2(rc.w);
            float rf[8] = {r0.x, r0.y, r1.x, r1.y, r2.x, r2.y, r3.x, r3.y};
            float d = rf[0] * qa.x + rf[1] * qa.y + rf[2] * qa.z + rf[3] * qa.w
                    + rf[4] * qb.x + rf[5] * qb.y + rf[6] * qb.z + rf[7] * qb.w;
            d += __shfl_xor(d, 8); d += __shfl_xor(d, 4);
            d += __shfl_xor(d, 2); d += __shfl_xor(d, 1);
            d += cadd;
            d = (d >= 0.f ? d : 0.01f * d) * scale;
            float mn = fmaxf(m, d);
            float r = __expf(m - mn);
            float p = __expf(d - mn);
            l = l * r + p;
            #pragma unroll
            for (int t = 0; t < 8; ++t) a[t] = a[t] * r + p * rf[t];
            m = mn;
        }
    }
    if (j == 0) { sm[g] = m; sl[g] = l; }
    #pragma unroll
    for (int t = 0; t < 8; ++t) sacc[g][j][t] = a[t];
    __syncthreads();
    if (threadIdx.x < 16) {
        float M2 = -INFINITY;
        #pragma unroll 4
        for (int gg = 0; gg < 16; ++gg) if (sl[gg] > 0.f) M2 = fmaxf(M2, sm[gg]);
        float L = 0.f;
        float acc[8] = {};
        #pragma unroll 4
        for (int gg = 0; gg < 16; ++gg) {
            float f = (sl[gg] > 0.f) ? __expf(sm[gg] - M2) : 0.f;
            L += f * sl[gg];
            #pragma unroll
            for (int t = 0; t < 8; ++t) acc[t] += f * sacc[gg][threadIdx.x][t];
        }
        float inv = (L > 0.f) ? 1.f / L : 0.f;
        float4 o1 = {acc[0] * inv, acc[1] * inv, acc[2] * inv, acc[3] * inv};
        float4 o2 = {acc[4] * inv, acc[5] * inv, acc[6] * inv, acc[7] * inv};
        ((float4*)(agg + (size_t)seg * 128 + 8 * threadIdx.x))[0] = o1;
        ((float4*)(agg + (size_t)seg * 128 + 8 * threadIdx.x))[1] = o2;
        if (threadIdx.x == 0) flag[seg] = (L > 0.f) ? 1.f : 0.f;
    }
}

// pred[m,c] = agg[m].W3c[:,c] + flag[m]*b3c[c] + bc[c]
__global__ void head2(const float* __restrict__ agg, const float* __restrict__ flag,
                      const float* __restrict__ W3c, const float* __restrict__ b3c,
                      const float* __restrict__ bc, float* __restrict__ out, int M) {
    int t = blockIdx.x * blockDim.x + threadIdx.x;
    if (t >= M * 10) return;
    int row = t / 10, c = t % 10;
    float acc = bc[c] + flag[row] * b3c[c];
    #pragma unroll 8
    for (int k = 0; k < 128; ++k)
        acc = fmaf(agg[(size_t)row * 128 + k], W3c[k * 10 + c], acc);
    out[t] = acc;
}

extern "C" void kernel_launch(void* const* d_in, const int* in_sizes, int n_in,
                              void* d_out, int out_size, void* d_ws, size_t ws_size,
                              hipStream_t stream) {
    const float* vfeat = (const float*)d_in[0];
    const float* efeat = (const float*)d_in[1];
    const int*   he    = (const int*)d_in[2];
    const int*   nd    = (const int*)d_in[3];
    const float* Wfl = (const float*)d_in[6],  *bfl = (const float*)d_in[7];
    const float* W1  = (const float*)d_in[8],  *b1  = (const float*)d_in[9];
    const float* W2  = (const float*)d_in[10], *b2  = (const float*)d_in[11];
    const float* W3  = (const float*)d_in[12], *b3  = (const float*)d_in[13];
    const float* W4  = (const float*)d_in[14], *b4  = (const float*)d_in[15];
    const float* W5  = (const float*)d_in[16], *b5  = (const float*)d_in[17];
    const float* W6  = (const float*)d_in[18], *b6  = (const float*)d_in[19];
    const float* Wc  = (const float*)d_in[20], *bc  = (const float*)d_in[21];
    float* out = (float*)d_out;
    float* ws  = (float*)d_ws;

    const int M = HY_M, N = HY_N, E = HY_E;

    // -------- workspace layout (float units) --------
    float* qt_e  = ws + 0;         // 1,280,000
    float* agg   = ws + 1280000;   // 1,280,000
    float* c_e   = ws + 2560000;   // 10,000
    float* ck    = ws + 2570000;   // 10,000
    float* flag  = ws + 2580000;   // 10,000
    float* W2T   = ws + 2590000;   // 16384
    float* W4T   = ws + 2606384;   // 16384
    float* W12   = ws + 2622768;   // 16384
    float* W54   = ws + 2639152;   // 16384
    float* Wk    = ws + 2655536;   // 16384
    float* Wv    = ws + 2671920;   // 16384
    float* Wq    = ws + 2688304;   // 16384
    float* W3c   = ws + 2704688;   // 1280
    float* b3c   = ws + 2705968;   // 16
    float* b12v  = ws + 2705984;   // 128
    float* w1b2  = ws + 2706112;   // 128
    float* s12   = ws + 2706240;   // 4
    float* b54v  = ws + 2706244;   // 128
    float* w5b4  = ws + 2706372;   // 128
    float* s54   = ws + 2706500;   // 4
    float* bk    = ws + 2706504;   // 128
    float* bv    = ws + 2706632;   // 128
    float* bq    = ws + 2706760;   // 128
    float* u_c   = ws + 2706888;   // 128
    float* u_k   = ws + 2707016;   // 128
    float* t_c   = ws + 2707144;   // 4
    float* t_k   = ws + 2707148;   // 4
    float* zeros = ws + 2707152;   // 128
    unsigned int* kv_bf = (unsigned int*)(ws + 2707280);   // M*128 = 1,280,000 words
    unsigned int* fv_bf = kv_bf + (size_t)M * 128;         // N*64 = 6,400,000 words
    int* nd_off = (int*)(fv_bf + (size_t)N * 64);          // 100,001
    int* he_off = nd_off + 100001;                          // 10,001
    int* nd_adj = he_off + 10001;                           // 640,000
    int* he_adj = nd_adj + 640000;                          // 640,000
    int* nperm  = he_adj + 640000;                          // 100,000
    unsigned int* stN = (unsigned int*)(nperm + 100000);    // 640,000
    unsigned int* stM = stN + 640000;                       // 640,000
    int* gcntN = (int*)(stM + 640000);                      // 256
    int* gcntM = gcntN + 256;                               // 256
    int* gcurN = gcntM + 256;                               // 256
    int* gcurM = gcurN + 256;                               // 256
    int* dcnt  = gcurM + 256;                               // 64
    int* dcur  = dcnt + 64;                                 // 64
    int* coffN = dcur + 64;                                 // 256 (197 used)
    int* coffM = coffN + 256;                               // 256 (158 used)

    const float scale = 0.08838834764831843f;  // 1/sqrt(128)
    const int nchunk = (E + 4095) / 4096;      // 157

    // -------- CSR build (both orientations) --------
    zero_ints<<<5, 256, 0, stream>>>(gcntN, 1152);   // gcnt/gcur + dcnt/dcur
    coarse_hist<<<nchunk, 256, 0, stream>>>(nd, he, gcntN, gcntM, E);
    coarse_scan<<<2, 256, 0, stream>>>(gcntN, gcntM, coffN, coffM, E);
    part_scatter<<<nchunk, 256, 0, stream>>>(nd, he, coffN, coffM,
                                             gcurN, gcurM, stN, stM, E);
    bucket_build<<<NB_N + NB_M, 256, 0, stream>>>(stN, stM, coffN, coffM,
                                                  nd_off, he_off, nd_adj, he_adj);

    // -------- degree-sorted node permutation --------
    deg_hist<<<(N + 255) / 256, 256, 0, stream>>>(nd_off, dcnt, N);
    deg_scan<<<1, 64, 0, stream>>>(dcnt, dcur);
    deg_scatter<<<(N + 255) / 256, 256, 0, stream>>>(nd_off, dcur, nperm, N);

    // -------- weight precomputes --------
    transpose2<<<dim3(64, 2), 256, 0, stream>>>(W2, W4, W2T, W4T);
    fillk<<<1, 128, 0, stream>>>(zeros, 0.f, 128);
    prep_vecs<<<1, 256, 0, stream>>>(W1, W2, b1, b2, b12v, w1b2, s12);
    prep_vecs<<<1, 256, 0, stream>>>(W5, W4, b5, b4, b54v, w5b4, s54);
    gemm_pair<<<dim3(2, 2), 512, 0, stream>>>(W1, W2T, W12, W5, W4T, W54, zeros);
    gemm_trip<<<dim3(2, 3), 512, 0, stream>>>(Wfl, W54, W6, W12, Wk, Wv, Wq, zeros);
    prep_fold<<<1, 256, 0, stream>>>(Wfl, bfl, W54, b54v, W6, b6, W12, b12v,
                                     w1b2, s12, w5b4, s54,
                                     bk, bv, bq, u_c, u_k, t_c, t_k);
    prep_w3c<<<6, 256, 0, stream>>>(W3, Wc, b3, W3c, b3c);

    // -------- M-row dense layer (single batched GEMM over efeat) --------
    gemm_m<<<dim3((M + 31) / 32, 6), 256, 0, stream>>>(
        efeat, Wk, bk, Wv, bv, Wq, bq, (unsigned short*)kv_bf, qt_e, M);
    dotc2<<<(M * 64 + 255) / 256, 256, 0, stream>>>(efeat, u_c, t_c, u_k, t_k,
                                                    c_e, ck, M);

    // -------- stage 1: hyperedge -> node --------
    attn_s1<<<(N * 16 + 255) / 256, 256, 0, stream>>>(
        vfeat, kv_bf, ck, nd_off, nd_adj, nperm, fv_bf, N, scale);

    // -------- stage 2: node -> hyperedge --------
    attn_s2<<<M, 256, 0, stream>>>(qt_e, c_e, fv_bf, he_off, he_adj, agg, flag, scale);

    // -------- head --------
    head2<<<(M * 10 + 255) / 256, 256, 0, stream>>>(agg, flag, W3c, b3c, bc, out, M);
}

// Round 11
// 212.352 us; speedup vs baseline: 2.8178x; 1.1580x over previous
//
#include <hip/hip_runtime.h>
#include <hip/hip_bf16.h>
#include <math.h>

// ---------------------------------------------------------------------------
// Seq_HyGAN round 11:
//  * attn_s1/attn_s2: 2-edge merged online softmax (1 rescale per PAIR:
//    mn=max3(m,d1,d2); a = fmaf(p2,v2,fmaf(p1,v1,a*r))) + 2-row prefetch.
//  * launch fusion 20->15: prep_a = transpose2+fillk+prep_vecs x2+prep_w3c;
//    deg_hist folded into bucket_build; prep_fold folded into gemm_trip y=3.
//  * CSR counting sort, gemm_m, Wfl/W-folds, degree-sorted nperm unchanged.
// ---------------------------------------------------------------------------

#define HY_M 10000
#define HY_N 100000
#define HY_E 640000

#define SH_N 9              // node bucket width 512
#define NB_N 196            // ceil(100000/512)
#define SH_M 6              // hedge bucket width 64
#define NB_M 157            // ceil(10000/64)

// ---- bf16 helpers (manual, RN) ----
__device__ __forceinline__ unsigned int f2bf(float x) {
    unsigned int u = __float_as_uint(x);
    return (u + 0x7fffu + ((u >> 16) & 1u)) >> 16;
}
__device__ __forceinline__ float2 bf2x2(unsigned int w) {
    float lo = __uint_as_float(w << 16);
    float hi = __uint_as_float(w & 0xffff0000u);
    return make_float2(lo, hi);
}
__device__ __forceinline__ float dot8(uint4 kw, float4 qa, float4 qb) {
    float2 k0 = bf2x2(kw.x), k1 = bf2x2(kw.y), k2 = bf2x2(kw.z), k3 = bf2x2(kw.w);
    return k0.x * qa.x + k0.y * qa.y + k1.x * qa.z + k1.y * qa.w
         + k2.x * qb.x + k2.y * qb.y + k3.x * qb.z + k3.y * qb.w;
}
__device__ __forceinline__ void unpack8(uint4 vw, float (&vf)[8]) {
    float2 v0 = bf2x2(vw.x), v1 = bf2x2(vw.y), v2 = bf2x2(vw.z), v3 = bf2x2(vw.w);
    vf[0] = v0.x; vf[1] = v0.y; vf[2] = v1.x; vf[3] = v1.y;
    vf[4] = v2.x; vf[5] = v2.y; vf[6] = v3.x; vf[7] = v3.y;
}

// ---------------- small utility kernels ----------------
__global__ void zero_ints(int* __restrict__ p, int n) {
    int i = blockIdx.x * blockDim.x + threadIdx.x;
    if (i < n) p[i] = 0;
}

// ---------------- CSR build: bucketed counting sort ----------------
__launch_bounds__(256)
__global__ void coarse_hist(const int* __restrict__ nd, const int* __restrict__ he,
                            int* __restrict__ gcntN, int* __restrict__ gcntM, int E) {
    __shared__ int hN[256], hM[256];
    const int t = threadIdx.x;
    hN[t] = 0; hM[t] = 0;
    __syncthreads();
    const int base = blockIdx.x * 4096;
    for (int i = t; i < 4096; i += 256) {
        int e = base + i;
        if (e < E) {
            atomicAdd(&hN[nd[e] >> SH_N], 1);
            atomicAdd(&hM[he[e] >> SH_M], 1);
        }
    }
    __syncthreads();
    if (hN[t]) atomicAdd(&gcntN[t], hN[t]);
    if (hM[t]) atomicAdd(&gcntM[t], hM[t]);
}

__global__ void coarse_scan(const int* __restrict__ gcntN, const int* __restrict__ gcntM,
                            int* __restrict__ coffN, int* __restrict__ coffM, int E) {
    __shared__ int s[256];
    const int* g = blockIdx.x ? gcntM : gcntN;
    int* o = blockIdx.x ? coffM : coffN;
    const int nb = blockIdx.x ? NB_M : NB_N;
    const int t = threadIdx.x;
    int v = (t < nb) ? g[t] : 0;
    int orig = v;
    s[t] = v; __syncthreads();
    for (int off = 1; off < 256; off <<= 1) {
        int x = (t >= off) ? s[t - off] : 0;
        __syncthreads(); s[t] += x; __syncthreads();
    }
    if (t < nb) o[t] = s[t] - orig;
    if (t == 0) o[nb] = E;
}

__launch_bounds__(256)
__global__ void part_scatter(const int* __restrict__ nd, const int* __restrict__ he,
                             const int* __restrict__ coffN, const int* __restrict__ coffM,
                             int* __restrict__ gcurN, int* __restrict__ gcurM,
                             unsigned int* __restrict__ stN, unsigned int* __restrict__ stM,
                             int E) {
    __shared__ int hN[256], hM[256];
    const int t = threadIdx.x;
    hN[t] = 0; hM[t] = 0;
    __syncthreads();
    const int base = blockIdx.x * 4096;
    for (int i = t; i < 4096; i += 256) {
        int e = base + i;
        if (e < E) {
            atomicAdd(&hN[nd[e] >> SH_N], 1);
            atomicAdd(&hM[he[e] >> SH_M], 1);
        }
    }
    __syncthreads();
    int cN = hN[t], cM = hM[t];
    __syncthreads();
    if (cN) hN[t] = coffN[t] + atomicAdd(&gcurN[t], cN);
    if (cM) hM[t] = coffM[t] + atomicAdd(&gcurM[t], cM);
    __syncthreads();
    for (int i = t; i < 4096; i += 256) {
        int e = base + i;
        if (e < E) {
            int d = nd[e], h = he[e];
            int pN = atomicAdd(&hN[d >> SH_N], 1);
            stN[pN] = ((unsigned int)(d & 511) << 14) | (unsigned int)h;
            int pM = atomicAdd(&hM[h >> SH_M], 1);
            stM[pM] = ((unsigned int)(h & 63) << 17) | (unsigned int)d;
        }
    }
}

// + folded node-degree histogram (feeds nperm build)
__launch_bounds__(256)
__global__ void bucket_build(const unsigned int* __restrict__ stN,
                             const unsigned int* __restrict__ stM,
                             const int* __restrict__ coffN, const int* __restrict__ coffM,
                             int* __restrict__ nd_off, int* __restrict__ he_off,
                             int* __restrict__ nd_adj, int* __restrict__ he_adj,
                             int* __restrict__ dcntg) {
    __shared__ int cnt[512];
    __shared__ int cur[512];
    __shared__ int ps[256];
    __shared__ int dh[64];
    int b = blockIdx.x;
    const int t = threadIdx.x;
    const unsigned int* st; const int* coff; int* offout; int* adj;
    int dmin, dcnt2, sshift; unsigned int smask; int ntot;
    const bool isN = b < NB_N;
    if (isN) {
        st = stN; coff = coffN; offout = nd_off; adj = nd_adj;
        dmin = b << SH_N; dcnt2 = min(512, HY_N - dmin);
        sshift = 14; smask = 0x3FFFu; ntot = HY_N;
    } else {
        b -= NB_N;
        st = stM; coff = coffM; offout = he_off; adj = he_adj;
        dmin = b << SH_M; dcnt2 = min(64, HY_M - dmin);
        sshift = 17; smask = 0x1FFFFu; ntot = HY_M;
    }
    const int cbase = coff[b], cend = coff[b + 1];
    cnt[t] = 0; cnt[t + 256] = 0;
    if (t < 64) dh[t] = 0;
    __syncthreads();
    for (int k = cbase + t; k < cend; k += 256)
        atomicAdd(&cnt[st[k] >> sshift], 1);
    __syncthreads();
    int a0 = cnt[2 * t], a1 = cnt[2 * t + 1];
    int pair = a0 + a1;
    ps[t] = pair;
    __syncthreads();
    for (int off = 1; off < 256; off <<= 1) {
        int x = (t >= off) ? ps[t - off] : 0;
        __syncthreads(); ps[t] += x; __syncthreads();
    }
    int excl = ps[t] - pair;
    cur[2 * t]     = cbase + excl;
    cur[2 * t + 1] = cbase + excl + a0;
    __syncthreads();
    for (int i = t; i < dcnt2; i += 256) offout[dmin + i] = cur[i];
    if (t == 0 && dmin + dcnt2 == ntot) offout[ntot] = cend;
    if (isN) {                                     // degree histogram (nperm)
        for (int i = t; i < dcnt2; i += 256)
            atomicAdd(&dh[min(cnt[i], 63)], 1);
    }
    __syncthreads();
    if (isN && t < 64 && dh[t]) atomicAdd(&dcntg[t], dh[t]);
    for (int k = cbase + t; k < cend; k += 256) {
        unsigned int w = st[k];
        int pos = atomicAdd(&cur[w >> sshift], 1);
        adj[pos] = (int)(w & smask);
    }
}

// ---------------- degree-sorted node permutation ----------------
__global__ void deg_scan(const int* __restrict__ dcnt, int* __restrict__ dcur) {
    int t = threadIdx.x;   // 64 threads = 1 wave
    int v = dcnt[t];
    int s = v;
    for (int o = 1; o < 64; o <<= 1) {
        int x = __shfl_up(s, o, 64);
        if (t >= o) s += x;
    }
    dcur[t] = s - v;       // exclusive
}

__launch_bounds__(256)
__global__ void deg_scatter(const int* __restrict__ off, int* __restrict__ dcur,
                            int* __restrict__ nperm, int n) {
    __shared__ int h[64];
    __shared__ int basev[64];
    int t = threadIdx.x;
    if (t < 64) h[t] = 0;
    __syncthreads();
    int i = blockIdx.x * blockDim.x + t;
    int bin = 0, lpos = 0;
    bool valid = i < n;
    if (valid) {
        bin = min(off[i + 1] - off[i], 63);
        lpos = atomicAdd(&h[bin], 1);
    }
    __syncthreads();
    if (t < 64 && h[t]) basev[t] = atomicAdd(&dcur[t], h[t]);
    __syncthreads();
    if (valid) nperm[basev[bin] + lpos] = i;
}

// ---------------- f32 GEMM core for 128x128 weight products ----------------
__device__ __forceinline__ void gemm_accum(const float* __restrict__ A,
        const float* __restrict__ W, int nrows, float* wlds,
        float (&acc)[4][4], int row0) {
    const int tid = threadIdx.x;
    const int cg = tid & 31;
    for (int i = tid; i < 4096; i += 512)
        ((float4*)wlds)[i] = ((const float4*)W)[i];
    __syncthreads();
    const float4* A0 = (const float4*)(A + (size_t)min(row0 + 0, nrows - 1) * 128);
    const float4* A1 = (const float4*)(A + (size_t)min(row0 + 1, nrows - 1) * 128);
    const float4* A2 = (const float4*)(A + (size_t)min(row0 + 2, nrows - 1) * 128);
    const float4* A3 = (const float4*)(A + (size_t)min(row0 + 3, nrows - 1) * 128);
    #pragma unroll 2
    for (int kq = 0; kq < 32; ++kq) {
        float4 ar[4] = {A0[kq], A1[kq], A2[kq], A3[kq]};
        const float4* wk = (const float4*)(wlds + kq * 512);
        float4 wr[4] = {wk[cg], wk[32 + cg], wk[64 + cg], wk[96 + cg]};
        #pragma unroll
        for (int r = 0; r < 4; ++r) {
            float av[4] = {ar[r].x, ar[r].y, ar[r].z, ar[r].w};
            #pragma unroll
            for (int j = 0; j < 4; ++j) {
                float wv[4] = {wr[j].x, wr[j].y, wr[j].z, wr[j].w};
                #pragma unroll
                for (int c = 0; c < 4; ++c)
                    acc[r][c] = fmaf(av[j], wv[c], acc[r][c]);
            }
        }
    }
}

__device__ __forceinline__ void gemm_store_f32(const float* __restrict__ b,
        float* __restrict__ Cf, int nrows, float (&acc)[4][4], int row0) {
    const int cg = threadIdx.x & 31;
    const float4 bv = ((const float4*)b)[cg];
    #pragma unroll
    for (int r = 0; r < 4; ++r) {
        int gr = row0 + r;
        if (gr < nrows) {
            float4 o = {acc[r][0] + bv.x, acc[r][1] + bv.y,
                        acc[r][2] + bv.z, acc[r][3] + bv.w};
            ((float4*)(Cf + (size_t)gr * 128))[cg] = o;
        }
    }
}

// y=0: W12=W1@W2T ; y=1: W54=W5@W4T
__launch_bounds__(512)
__global__ void gemm_pair(const float* __restrict__ Aa, const float* __restrict__ Wa,
                          float* __restrict__ Ca,
                          const float* __restrict__ Ab, const float* __restrict__ Wb,
                          float* __restrict__ Cb2, const float* __restrict__ zb) {
    __shared__ __align__(16) float wlds[16384];
    const int rs = threadIdx.x >> 5;
    const int row0 = blockIdx.x * 64 + rs * 4;
    const float* A = blockIdx.y ? Ab : Aa;
    const float* W = blockIdx.y ? Wb : Wa;
    float* C = blockIdx.y ? Cb2 : Ca;
    float acc[4][4] = {};
    gemm_accum(A, W, 128, wlds, acc, row0);
    gemm_store_f32(zb, C, 128, acc, row0);
}

// y=0..2: Wk/Wv/Wq = Wfl @ {W54,W6,W12} ; y=3,x=0: prep_fold (bias/dot folds)
__launch_bounds__(512)
__global__ void gemm_trip(const float* __restrict__ Wfl, const float* __restrict__ bfl,
        const float* __restrict__ W54, const float* __restrict__ b54v,
        const float* __restrict__ W6, const float* __restrict__ b6,
        const float* __restrict__ W12, const float* __restrict__ b12v,
        const float* __restrict__ w1b2, const float* __restrict__ s12,
        const float* __restrict__ w5b4, const float* __restrict__ s54,
        float* __restrict__ Wk, float* __restrict__ Wv, float* __restrict__ Wq,
        float* __restrict__ bk, float* __restrict__ bv, float* __restrict__ bq,
        float* __restrict__ u_c, float* __restrict__ u_k,
        float* __restrict__ t_c, float* __restrict__ t_k,
        const float* __restrict__ zb) {
    __shared__ __align__(16) float wlds[16384];
    const int y = blockIdx.y;
    if (y == 3) {
        if (blockIdx.x != 0) return;
        int t = threadIdx.x;
        if (t < 128) {
            float a1 = 0.f, a2 = 0.f, a3 = 0.f;
            for (int j = 0; j < 128; ++j) {
                float f = bfl[j];
                a1 += f * W54[j * 128 + t];
                a2 += f * W6[j * 128 + t];
                a3 += f * W12[j * 128 + t];
            }
            bk[t] = a1 + b54v[t];
            bv[t] = a2 + b6[t];
            bq[t] = a3 + b12v[t];
        } else if (t < 256) {
            int k = t - 128;
            float a1 = 0.f, a2 = 0.f;
            for (int j = 0; j < 128; ++j) {
                float f = Wfl[k * 128 + j];
                a1 += f * w1b2[j];
                a2 += f * w5b4[j];
            }
            u_c[k] = a1;
            u_k[k] = a2;
        }
        if (t == 0) {
            float a1 = 0.f, a2 = 0.f;
            for (int j = 0; j < 128; ++j) {
                a1 += bfl[j] * w1b2[j];
                a2 += bfl[j] * w5b4[j];
            }
            *t_c = a1 + *s12;
            *t_k = a2 + *s54;
        }
        return;
    }
    const int rs = threadIdx.x >> 5;
    const int row0 = blockIdx.x * 64 + rs * 4;
    const float* W = y == 0 ? W54 : (y == 1 ? W6 : W12);
    float* C = y == 0 ? Wk : (y == 1 ? Wv : Wq);
    float acc[4][4] = {};
    gemm_accum(Wfl, W, 128, wlds, acc, row0);
    gemm_store_f32(zb, C, 128, acc, row0);
}

// ---------------- main M-row batched GEMM: efeat -> kv table + qt_e ----------
__launch_bounds__(256)
__global__ void gemm_m(const float* __restrict__ A,
        const float* __restrict__ Wk, const float* __restrict__ bk,
        const float* __restrict__ Wv, const float* __restrict__ bvv,
        const float* __restrict__ Wq, const float* __restrict__ bq,
        unsigned short* __restrict__ kv, float* __restrict__ qt, int nrows) {
    __shared__ __align__(16) float wlds[128 * 64];
    const int tid = threadIdx.x;
    const int mat = blockIdx.y >> 1;
    const int half = blockIdx.y & 1;
    const float* W = mat == 0 ? Wk : (mat == 1 ? Wv : Wq);
    const float* bb = mat == 0 ? bk : (mat == 1 ? bvv : bq);
    const float4* W4 = (const float4*)W;
    float4* wl4 = (float4*)wlds;
    for (int i = tid; i < 2048; i += 256)
        wl4[i] = W4[(i >> 4) * 32 + half * 16 + (i & 15)];
    __syncthreads();
    const int cg = tid & 15;
    const int rs = tid >> 4;
    const int row0 = blockIdx.x * 32 + rs * 2;
    const float4* A0 = (const float4*)(A + (size_t)min(row0, nrows - 1) * 128);
    const float4* A1 = (const float4*)(A + (size_t)min(row0 + 1, nrows - 1) * 128);
    float acc[2][4] = {};
    #pragma unroll 4
    for (int kq = 0; kq < 32; ++kq) {
        float4 a0 = A0[kq], a1 = A1[kq];
        float av0[4] = {a0.x, a0.y, a0.z, a0.w};
        float av1[4] = {a1.x, a1.y, a1.z, a1.w};
        #pragma unroll
        for (int jj = 0; jj < 4; ++jj) {
            float4 w4 = wl4[(4 * kq + jj) * 16 + cg];
            float wv4[4] = {w4.x, w4.y, w4.z, w4.w};
            #pragma unroll
            for (int c = 0; c < 4; ++c) {
                acc[0][c] = fmaf(av0[jj], wv4[c], acc[0][c]);
                acc[1][c] = fmaf(av1[jj], wv4[c], acc[1][c]);
            }
        }
    }
    const float4 bv4 = ((const float4*)bb)[half * 16 + cg];
    #pragma unroll
    for (int r = 0; r < 2; ++r) {
        int gr = row0 + r;
        if (gr < nrows) {
            float o0 = acc[r][0] + bv4.x, o1 = acc[r][1] + bv4.y;
            float o2 = acc[r][2] + bv4.z, o3 = acc[r][3] + bv4.w;
            if (mat == 2) {
                float4 o = {o0, o1, o2, o3};
                ((float4*)(qt + (size_t)gr * 128))[half * 16 + cg] = o;
            } else {
                uint2 pk;
                pk.x = f2bf(o0) | (f2bf(o1) << 16);
                pk.y = f2bf(o2) | (f2bf(o3) << 16);
                *(uint2*)(kv + (size_t)gr * 256 + mat * 128 + half * 64 + cg * 4) = pk;
            }
        }
    }
}

// ---------------- fused precompute kernel (137 blocks) ----------------
__device__ __forceinline__ void prep_vecs_body(const float* WX, const float* WY,
        const float* bX, const float* bY, float* bXY, float* wXbY, float* sXY, int t) {
    if (t < 128) {
        float acc = 0.f;
        for (int j = 0; j < 128; ++j) acc += WY[t * 128 + j] * bX[j];
        bXY[t] = acc;
    } else {
        int k = t - 128;
        float acc = 0.f;
        for (int j = 0; j < 128; ++j) acc += WX[k * 128 + j] * bY[j];
        wXbY[k] = acc;
    }
    if (t == 0) {
        float acc = 0.f;
        for (int j = 0; j < 128; ++j) acc += bX[j] * bY[j];
        *sXY = acc;
    }
}

__global__ void prep_a(const float* __restrict__ W1, const float* __restrict__ b1,
                       const float* __restrict__ W2, const float* __restrict__ b2,
                       const float* __restrict__ W3, const float* __restrict__ b3,
                       const float* __restrict__ W4, const float* __restrict__ b4,
                       const float* __restrict__ W5, const float* __restrict__ b5,
                       const float* __restrict__ Wc,
                       float* __restrict__ W2T, float* __restrict__ W4T,
                       float* __restrict__ b12v, float* __restrict__ w1b2,
                       float* __restrict__ s12,
                       float* __restrict__ b54v, float* __restrict__ w5b4,
                       float* __restrict__ s54,
                       float* __restrict__ W3c, float* __restrict__ b3c,
                       float* __restrict__ zeros) {
    const int x = blockIdx.x, t = threadIdx.x;
    if (x < 64) {
        int i = x * 256 + t;
        W2T[(i & 127) * 128 + (i >> 7)] = W2[i];
    } else if (x < 128) {
        int i = (x - 64) * 256 + t;
        W4T[(i & 127) * 128 + (i >> 7)] = W4[i];
    } else if (x == 128) {
        prep_vecs_body(W1, W2, b1, b2, b12v, w1b2, s12, t);
    } else if (x == 129) {
        prep_vecs_body(W5, W4, b5, b4, b54v, w5b4, s54, t);
    } else if (x < 136) {
        int i = (x - 130) * 256 + t;
        if (i < 1280) {
            int k = i / 10, c = i % 10;
            float acc = 0.f;
            for (int j = 0; j < 128; ++j) acc += W3[k * 128 + j] * Wc[j * 10 + c];
            W3c[i] = acc;
        } else if (i < 1290) {
            int c = i - 1280;
            float acc = 0.f;
            for (int j = 0; j < 128; ++j) acc += b3[j] * Wc[j * 10 + c];
            b3c[c] = acc;
        }
    } else {
        if (t < 128) zeros[t] = 0.f;
    }
}

// two dots per efeat row: c_e = X.u1 + t1 ; ck = X.u2 + t2
__launch_bounds__(256)
__global__ void dotc2(const float* __restrict__ X,
                      const float* __restrict__ u1, const float* __restrict__ t1v,
                      const float* __restrict__ u2, const float* __restrict__ t2v,
                      float* __restrict__ o1, float* __restrict__ o2, int M) {
    int w = (blockIdx.x * blockDim.x + threadIdx.x) >> 6;
    int lane = threadIdx.x & 63;
    if (w >= M) return;
    float2 r = ((const float2*)(X + (size_t)w * 128))[lane];
    float2 a1 = ((const float2*)u1)[lane];
    float2 a2 = ((const float2*)u2)[lane];
    float d1 = r.x * a1.x + r.y * a1.y;
    float d2 = r.x * a2.x + r.y * a2.y;
    #pragma unroll
    for (int o = 32; o; o >>= 1) {
        d1 += __shfl_xor(d1, o, 64);
        d2 += __shfl_xor(d2, o, 64);
    }
    if (lane == 0) { o1[w] = d1 + *t1v; o2[w] = d2 + *t2v; }
}

// ---------------- stage 1: hyperedge -> node --------------------------------
// 16-lane group per segment (degree-sorted via nperm); 2-edge merged softmax.
__launch_bounds__(256)
__global__ void attn_s1(const float* __restrict__ vf,          // N x 128 f32
                        const unsigned int* __restrict__ kv,   // M x 128 words (kt|v)
                        const float* __restrict__ ck,          // M
                        const int* __restrict__ off, const int* __restrict__ adj,
                        const int* __restrict__ nperm,
                        unsigned int* __restrict__ fv,         // N x 64 words
                        int nseg, float scale) {
    int slot = (blockIdx.x * blockDim.x + threadIdx.x) >> 4;
    int j = threadIdx.x & 15;
    if (slot >= nseg) return;
    int seg = nperm[slot];
    int beg = off[seg], end = off[seg + 1];
    const float4 qa = ((const float4*)(vf + (size_t)seg * 128 + 8 * j))[0];
    const float4 qb = ((const float4*)(vf + (size_t)seg * 128 + 8 * j))[1];
    float m = -INFINITY, l = 0.f;
    float a[8] = {};
    int i = beg;
    const int cnt = end - beg;
    if (cnt >= 2) {
        int s0 = adj[i], s1 = adj[i + 1];
        uint4 kw0 = ((const uint4*)(kv + (size_t)s0 * 128))[j];
        uint4 vw0 = ((const uint4*)(kv + (size_t)s0 * 128 + 64))[j];
        float c0 = ck[s0];
        uint4 kw1 = ((const uint4*)(kv + (size_t)s1 * 128))[j];
        uint4 vw1 = ((const uint4*)(kv + (size_t)s1 * 128 + 64))[j];
        float c1 = ck[s1];
        for (; i + 1 < end; i += 2) {
            uint4 ka = kw0, va = vw0, kb = kw1, vb = vw1;
            float ca = c0, cb = c1;
            if (i + 3 < end) {                     // prefetch next pair
                int t0 = adj[i + 2], t1 = adj[i + 3];
                kw0 = ((const uint4*)(kv + (size_t)t0 * 128))[j];
                vw0 = ((const uint4*)(kv + (size_t)t0 * 128 + 64))[j];
                c0 = ck[t0];
                kw1 = ((const uint4*)(kv + (size_t)t1 * 128))[j];
                vw1 = ((const uint4*)(kv + (size_t)t1 * 128 + 64))[j];
                c1 = ck[t1];
            } else if (i + 2 < end) {              // prefetch odd tail
                int t0 = adj[i + 2];
                kw0 = ((const uint4*)(kv + (size_t)t0 * 128))[j];
                vw0 = ((const uint4*)(kv + (size_t)t0 * 128 + 64))[j];
                c0 = ck[t0];
            }
            float d1 = dot8(ka, qa, qb);
            float d2 = dot8(kb, qa, qb);
            d1 += __shfl_xor(d1, 8); d2 += __shfl_xor(d2, 8);
            d1 += __shfl_xor(d1, 4); d2 += __shfl_xor(d2, 4);
            d1 += __shfl_xor(d1, 2); d2 += __shfl_xor(d2, 2);
            d1 += __shfl_xor(d1, 1); d2 += __shfl_xor(d2, 1);
            d1 += ca; d2 += cb;
            d1 = (d1 >= 0.f ? d1 : 0.01f * d1) * scale;
            d2 = (d2 >= 0.f ? d2 : 0.01f * d2) * scale;
            float mn = fmaxf(fmaxf(m, d1), d2);
            float r  = __expf(m - mn);             // first pair: exp(-inf)=0
            float p1 = __expf(d1 - mn);
            float p2 = __expf(d2 - mn);
            l = l * r + p1 + p2;
            float v1[8], v2[8];
            unpack8(va, v1); unpack8(vb, v2);
            #pragma unroll
            for (int t = 0; t < 8; ++t)
                a[t] = fmaf(p2, v2[t], fmaf(p1, v1[t], a[t] * r));
            m = mn;
        }
        if (i < end) {                             // odd tail (prefetched in slot 0)
            float d = dot8(kw0, qa, qb);
            d += __shfl_xor(d, 8); d += __shfl_xor(d, 4);
            d += __shfl_xor(d, 2); d += __shfl_xor(d, 1);
            d += c0;
            d = (d >= 0.f ? d : 0.01f * d) * scale;
            float mn = fmaxf(m, d);
            float r = __expf(m - mn);
            float p = __expf(d - mn);
            l = l * r + p;
            float v1[8]; unpack8(vw0, v1);
            #pragma unroll
            for (int t = 0; t < 8; ++t)
                a[t] = fmaf(p, v1[t], a[t] * r);
            m = mn;
        }
    } else if (cnt == 1) {
        int s0 = adj[i];
        uint4 kw0 = ((const uint4*)(kv + (size_t)s0 * 128))[j];
        uint4 vw0 = ((const uint4*)(kv + (size_t)s0 * 128 + 64))[j];
        float d = dot8(kw0, qa, qb);
        d += __shfl_xor(d, 8); d += __shfl_xor(d, 4);
        d += __shfl_xor(d, 2); d += __shfl_xor(d, 1);
        d += ck[s0];
        d = (d >= 0.f ? d : 0.01f * d) * scale;
        l = 1.f;
        float v1[8]; unpack8(vw0, v1);
        #pragma unroll
        for (int t = 0; t < 8; ++t) a[t] = v1[t];
    }
    float inv = (l > 0.f) ? 1.f / l : 0.f;
    uint4 o;
    o.x = f2bf(a[0] * inv) | (f2bf(a[1] * inv) << 16);
    o.y = f2bf(a[2] * inv) | (f2bf(a[3] * inv) << 16);
    o.z = f2bf(a[4] * inv) | (f2bf(a[5] * inv) << 16);
    o.w = f2bf(a[6] * inv) | (f2bf(a[7] * inv) << 16);
    ((uint4*)(fv + (size_t)seg * 64))[j] = o;
}

// ---------------- stage 2: node -> hyperedge --------------------------------
// 16 groups per block stride the edge list; 2-edge merged softmax; LDS merge.
__launch_bounds__(256)
__global__ void attn_s2(const float* __restrict__ QT, const float* __restrict__ cvec,
                        const unsigned int* __restrict__ fv,
                        const int* __restrict__ off, const int* __restrict__ adj,
                        float* __restrict__ agg, float* __restrict__ flag, float scale) {
    __shared__ float sm[16], sl[16];
    __shared__ float sacc[16][16][9];
    const int seg = blockIdx.x;
    const int g = threadIdx.x >> 4;
    const int j = threadIdx.x & 15;
    const int beg = off[seg], end = off[seg + 1];
    const float4 qa = ((const float4*)(QT + (size_t)seg * 128 + 8 * j))[0];
    const float4 qb = ((const float4*)(QT + (size_t)seg * 128 + 8 * j))[1];
    const float cadd = cvec[seg];
    float m = -INFINITY, l = 0.f;
    float a[8] = {};
    int it = beg + g;
    if (it + 16 < end) {
        int s0 = adj[it], s1 = adj[it + 16];
        uint4 rw0 = ((const uint4*)(fv + (size_t)s0 * 64))[j];
        uint4 rw1 = ((const uint4*)(fv + (size_t)s1 * 64))[j];
        for (; it + 16 < end; it += 32) {
            uint4 ra = rw0, rb = rw1;
            if (it + 48 < end) {
                int t0 = adj[it + 32], t1 = adj[it + 48];
                rw0 = ((const uint4*)(fv + (size_t)t0 * 64))[j];
                rw1 = ((const uint4*)(fv + (size_t)t1 * 64))[j];
            } else if (it + 32 < end) {
                int t0 = adj[it + 32];
                rw0 = ((const uint4*)(fv + (size_t)t0 * 64))[j];
            }
            float v1[8], v2[8];
            unpack8(ra, v1); unpack8(rb, v2);
            float d1 = v1[0] * qa.x + v1[1] * qa.y + v1[2] * qa.z + v1[3] * qa.w
                     + v1[4] * qb.x + v1[5] * qb.y + v1[6] * qb.z + v1[7] * qb.w;
            float d2 = v2[0] * qa.x + v2[1] * qa.y + v2[2] * qa.z + v2[3] * qa.w
                     + v2[4] * qb.x + v2[5] * qb.y + v2[6] * qb.z + v2[7] * qb.w;
            d1 += __shfl_xor(d1, 8); d2 += __shfl_xor(d2, 8);
            d1 += __shfl_xor(d1, 4); d2 += __shfl_xor(d2, 4);
            d1 += __shfl_xor(d1, 2); d2 += __shfl_xor(d2, 2);
            d1 += __shfl_xor(d1, 1); d2 += __shfl_xor(d2, 1);
            d1 += cadd; d2 += cadd;
            d1 = (d1 >= 0.f ? d1 : 0.01f * d1) * scale;
            d2 = (d2 >= 0.f ? d2 : 0.01f * d2) * scale;
            float mn = fmaxf(fmaxf(m, d1), d2);
            float r  = __expf(m - mn);
            float p1 = __expf(d1 - mn);
            float p2 = __expf(d2 - mn);
            l = l * r + p1 + p2;
            #pragma unroll
            for (int t = 0; t < 8; ++t)
                a[t] = fmaf(p2, v2[t], fmaf(p1, v1[t], a[t] * r));
            m = mn;
        }
        if (it < end) {                            // tail (prefetched slot 0)
            float v1[8]; unpack8(rw0, v1);
            float d = v1[0] * qa.x + v1[1] * qa.y + v1[2] * qa.z + v1[3] * qa.w
                    + v1[4] * qb.x + v1[5] * qb.y + v1[6] * qb.z + v1[7] * qb.w;
            d += __shfl_xor(d, 8); d += __shfl_xor(d, 4);
            d += __shfl_xor(d, 2); d += __shfl_xor(d, 1);
            d += cadd;
            d = (d >= 0.f ? d : 0.01f * d) * scale;
            float mn = fmaxf(m, d);
            float r = __expf(m - mn);
            float p = __expf(d - mn);
            l = l * r + p;
            #pragma unroll
            for (int t = 0; t < 8; ++t) a[t] = fmaf(p, v1[t], a[t] * r);
            m = mn;
        }
    } else if (it < end) {                         // exactly one edge for group
        int s0 = adj[it];
        uint4 rw0 = ((const uint4*)(fv + (size_t)s0 * 64))[j];
        float v1[8]; unpack8(rw0, v1);
        float d = v1[0] * qa.x + v1[1] * qa.y + v1[2] * qa.z + v1[3] * qa.w
                + v1[4] * qb.x + v1[5] * qb.y + v1[6] * qb.z + v1[7] * qb.w;
        d += __shfl_xor(d, 8); d += __shfl_xor(d, 4);
        d += __shfl_xor(d, 2); d += __shfl_xor(d, 1);
        d += cadd;
        d = (d >= 0.f ? d : 0.01f * d) * scale;
        m = d; l = 1.f;
        #pragma unroll
        for (int t = 0; t < 8; ++t) a[t] = v1[t];
    }
    if (j == 0) { sm[g] = m; sl[g] = l; }
    #pragma unroll
    for (int t = 0; t < 8; ++t) sacc[g][j][t] = a[t];
    __syncthreads();
    if (threadIdx.x < 16) {
        float M2 = -INFINITY;
        #pragma unroll 4
        for (int gg = 0; gg < 16; ++gg) if (sl[gg] > 0.f) M2 = fmaxf(M2, sm[gg]);
        float L = 0.f;
        float acc[8] = {};
        #pragma unroll 4
        for (int gg = 0; gg < 16; ++gg) {
            float f = (sl[gg] > 0.f) ? __expf(sm[gg] - M2) : 0.f;
            L += f * sl[gg];
            #pragma unroll
            for (int t = 0; t < 8; ++t) acc[t] += f * sacc[gg][threadIdx.x][t];
        }
        float inv = (L > 0.f) ? 1.f / L : 0.f;
        float4 o1 = {acc[0] * inv, acc[1] * inv, acc[2] * inv, acc[3] * inv};
        float4 o2 = {acc[4] * inv, acc[5] * inv, acc[6] * inv, acc[7] * inv};
        ((float4*)(agg + (size_t)seg * 128 + 8 * threadIdx.x))[0] = o1;
        ((float4*)(agg + (size_t)seg * 128 + 8 * threadIdx.x))[1] = o2;
        if (threadIdx.x == 0) flag[seg] = (L > 0.f) ? 1.f : 0.f;
    }
}

// pred[m,c] = agg[m].W3c[:,c] + flag[m]*b3c[c] + bc[c]
__global__ void head2(const float* __restrict__ agg, const float* __restrict__ flag,
                      const float* __restrict__ W3c, const float* __restrict__ b3c,
                      const float* __restrict__ bc, float* __restrict__ out, int M) {
    int t = blockIdx.x * blockDim.x + threadIdx.x;
    if (t >= M * 10) return;
    int row = t / 10, c = t % 10;
    float acc = bc[c] + flag[row] * b3c[c];
    #pragma unroll 8
    for (int k = 0; k < 128; ++k)
        acc = fmaf(agg[(size_t)row * 128 + k], W3c[k * 10 + c], acc);
    out[t] = acc;
}

extern "C" void kernel_launch(void* const* d_in, const int* in_sizes, int n_in,
                              void* d_out, int out_size, void* d_ws, size_t ws_size,
                              hipStream_t stream) {
    const float* vfeat = (const float*)d_in[0];
    const float* efeat = (const float*)d_in[1];
    const int*   he    = (const int*)d_in[2];
    const int*   nd    = (const int*)d_in[3];
    const float* Wfl = (const float*)d_in[6],  *bfl = (const float*)d_in[7];
    const float* W1  = (const float*)d_in[8],  *b1  = (const float*)d_in[9];
    const float* W2  = (const float*)d_in[10], *b2  = (const float*)d_in[11];
    const float* W3  = (const float*)d_in[12], *b3  = (const float*)d_in[13];
    const float* W4  = (const float*)d_in[14], *b4  = (const float*)d_in[15];
    const float* W5  = (const float*)d_in[16], *b5  = (const float*)d_in[17];
    const float* W6  = (const float*)d_in[18], *b6  = (const float*)d_in[19];
    const float* Wc  = (const float*)d_in[20], *bc  = (const float*)d_in[21];
    float* out = (float*)d_out;
    float* ws  = (float*)d_ws;

    const int M = HY_M, N = HY_N, E = HY_E;

    // -------- workspace layout (float units) --------
    float* qt_e  = ws + 0;         // 1,280,000
    float* agg   = ws + 1280000;   // 1,280,000
    float* c_e   = ws + 2560000;   // 10,000
    float* ck    = ws + 2570000;   // 10,000
    float* flag  = ws + 2580000;   // 10,000
    float* W2T   = ws + 2590000;   // 16384
    float* W4T   = ws + 2606384;   // 16384
    float* W12   = ws + 2622768;   // 16384
    float* W54   = ws + 2639152;   // 16384
    float* Wk    = ws + 2655536;   // 16384
    float* Wv    = ws + 2671920;   // 16384
    float* Wq    = ws + 2688304;   // 16384
    float* W3c   = ws + 2704688;   // 1280
    float* b3c   = ws + 2705968;   // 16
    float* b12v  = ws + 2705984;   // 128
    float* w1b2  = ws + 2706112;   // 128
    float* s12   = ws + 2706240;   // 4
    float* b54v  = ws + 2706244;   // 128
    float* w5b4  = ws + 2706372;   // 128
    float* s54   = ws + 2706500;   // 4
    float* bk    = ws + 2706504;   // 128
    float* bv    = ws + 2706632;   // 128
    float* bq    = ws + 2706760;   // 128
    float* u_c   = ws + 2706888;   // 128
    float* u_k   = ws + 2707016;   // 128
    float* t_c   = ws + 2707144;   // 4
    float* t_k   = ws + 2707148;   // 4
    float* zeros = ws + 2707152;   // 128
    unsigned int* kv_bf = (unsigned int*)(ws + 2707280);   // M*128 words
    unsigned int* fv_bf = kv_bf + (size_t)M * 128;         // N*64 words
    int* nd_off = (int*)(fv_bf + (size_t)N * 64);          // 100,001
    int* he_off = nd_off + 100001;                          // 10,001
    int* nd_adj = he_off + 10001;                           // 640,000
    int* he_adj = nd_adj + 640000;                          // 640,000
    int* nperm  = he_adj + 640000;                          // 100,000
    unsigned int* stN = (unsigned int*)(nperm + 100000);    // 640,000
    unsigned int* stM = stN + 640000;                       // 640,000
    int* gcntN = (int*)(stM + 640000);                      // 256
    int* gcntM = gcntN + 256;                               // 256
    int* gcurN = gcntM + 256;                               // 256
    int* gcurM = gcurN + 256;                               // 256
    int* dcnt  = gcurM + 256;                               // 64
    int* dcur  = dcnt + 64;                                 // 64
    int* coffN = dcur + 64;                                 // 256 (197 used)
    int* coffM = coffN + 256;                               // 256 (158 used)

    const float scale = 0.08838834764831843f;  // 1/sqrt(128)
    const int nchunk = (E + 4095) / 4096;      // 157

    // -------- CSR build (both orientations) + degree hist --------
    zero_ints<<<5, 256, 0, stream>>>(gcntN, 1152);
    coarse_hist<<<nchunk, 256, 0, stream>>>(nd, he, gcntN, gcntM, E);
    coarse_scan<<<2, 256, 0, stream>>>(gcntN, gcntM, coffN, coffM, E);
    part_scatter<<<nchunk, 256, 0, stream>>>(nd, he, coffN, coffM,
                                             gcurN, gcurM, stN, stM, E);
    bucket_build<<<NB_N + NB_M, 256, 0, stream>>>(stN, stM, coffN, coffM,
                                                  nd_off, he_off, nd_adj, he_adj,
                                                  dcnt);
    deg_scan<<<1, 64, 0, stream>>>(dcnt, dcur);
    deg_scatter<<<(N + 255) / 256, 256, 0, stream>>>(nd_off, dcur, nperm, N);

    // -------- weight precomputes (fused) --------
    prep_a<<<137, 256, 0, stream>>>(W1, b1, W2, b2, W3, b3, W4, b4, W5, b5, Wc,
                                    W2T, W4T, b12v, w1b2, s12, b54v, w5b4, s54,
                                    W3c, b3c, zeros);
    gemm_pair<<<dim3(2, 2), 512, 0, stream>>>(W1, W2T, W12, W5, W4T, W54, zeros);
    gemm_trip<<<dim3(2, 4), 512, 0, stream>>>(Wfl, bfl, W54, b54v, W6, b6, W12, b12v,
                                              w1b2, s12, w5b4, s54,
                                              Wk, Wv, Wq, bk, bv, bq,
                                              u_c, u_k, t_c, t_k, zeros);

    // -------- M-row dense layer --------
    gemm_m<<<dim3((M + 31) / 32, 6), 256, 0, stream>>>(
        efeat, Wk, bk, Wv, bv, Wq, bq, (unsigned short*)kv_bf, qt_e, M);
    dotc2<<<(M * 64 + 255) / 256, 256, 0, stream>>>(efeat, u_c, t_c, u_k, t_k,
                                                    c_e, ck, M);

    // -------- stage 1: hyperedge -> node --------
    attn_s1<<<(N * 16 + 255) / 256, 256, 0, stream>>>(
        vfeat, kv_bf, ck, nd_off, nd_adj, nperm, fv_bf, N, scale);

    // -------- stage 2: node -> hyperedge --------
    attn_s2<<<M, 256, 0, stream>>>(qt_e, c_e, fv_bf, he_off, he_adj, agg, flag, scale);

    // -------- head --------
    head2<<<(M * 10 + 255) / 256, 256, 0, stream>>>(agg, flag, W3c, b3c, bc, out, M);
}